// Round 1
// baseline (1376.798 us; speedup 1.0000x reference)
//
#include <hip/hip_runtime.h>
#include <hip/hip_bf16.h>

#define NNODE 50000
#define NEDGE 250000

typedef __hip_bfloat16 bf16;

__device__ __forceinline__ float b2f(bf16 x){ return __bfloat162float(x); }
__device__ __forceinline__ bf16  f2b(float x){ return __float2bfloat16(x); }
__device__ __forceinline__ float sigm(float x){ return 1.0f/(1.0f+__expf(-x)); }
__device__ __forceinline__ unsigned f2ord(float f){ unsigned u=__float_as_uint(f); return (u&0x80000000u)? ~u : (u|0x80000000u); }
__device__ __forceinline__ float ord2f(unsigned u){ return __uint_as_float((u&0x80000000u)? (u&0x7fffffffu) : ~u); }
__device__ __forceinline__ float wred64(float v){
  #pragma unroll
  for(int o=32;o>0;o>>=1) v+=__shfl_xor(v,o,64);
  return v;
}
__device__ __forceinline__ float gred16(float v){
  v+=__shfl_xor(v,1,64); v+=__shfl_xor(v,2,64); v+=__shfl_xor(v,4,64); v+=__shfl_xor(v,8,64);
  return v;
}

// ---------------------------------------------------------------------------
// K1: per-node scalar path: Q,K (bf16) and NREC[0..256) = {S1(128), S2(64), sv(64)}
// 16 nodes per 256-thread block. 3125 blocks.
// ---------------------------------------------------------------------------
__global__ __launch_bounds__(256) void k1_node_scalar(
  const float* __restrict__ nf,
  const float* __restrict__ Wq, const float* __restrict__ bq,
  const float* __restrict__ Wk, const float* __restrict__ bk,
  const float* __restrict__ Wvs_w, const float* __restrict__ bvs,
  const float* __restrict__ w_ss, const float* __restrict__ w_ssg, const float* __restrict__ w_sv,
  bf16* __restrict__ Q, bf16* __restrict__ K, bf16* __restrict__ NREC)
{
  __shared__ float ns[16][128];
  __shared__ float vs[16][128];
  const int t = threadIdx.x;
  const int n0 = blockIdx.x * 16;
  for(int i=t;i<16*128;i+=256){ int nn=i>>7, c=i&127; ns[nn][c]=nf[(size_t)(n0+nn)*320+c]; }
  __syncthreads();
  // Phase A: Q,K column t (0..255)
  {
    float aq[16], ak[16];
    #pragma unroll
    for(int q=0;q<16;q++){aq[q]=0.f;ak[q]=0.f;}
    for(int i=0;i<128;i+=4){
      float wq0=Wq[i*256+t],wq1=Wq[(i+1)*256+t],wq2=Wq[(i+2)*256+t],wq3=Wq[(i+3)*256+t];
      float wk0=Wk[i*256+t],wk1=Wk[(i+1)*256+t],wk2=Wk[(i+2)*256+t],wk3=Wk[(i+3)*256+t];
      #pragma unroll
      for(int q=0;q<16;q++){
        const float4 x=*(const float4*)&ns[q][i];
        aq[q]+=x.x*wq0+x.y*wq1+x.z*wq2+x.w*wq3;
        ak[q]+=x.x*wk0+x.y*wk1+x.z*wk2+x.w*wk3;
      }
    }
    float bqv=bq[t], bkv=bk[t];
    #pragma unroll
    for(int q=0;q<16;q++){
      Q[(size_t)(n0+q)*256+t]=f2b(aq[q]+bqv);
      K[(size_t)(n0+q)*256+t]=f2b(ak[q]+bkv);
    }
  }
  // Phase B: Vs = ns@Wv_s + bv_s  (col t&127, node-half t>>7)
  {
    const int c=t&127, hf=t>>7;
    float a[8];
    #pragma unroll
    for(int q=0;q<8;q++)a[q]=0.f;
    for(int i=0;i<128;i+=4){
      float w0=Wvs_w[i*128+c],w1=Wvs_w[(i+1)*128+c],w2=Wvs_w[(i+2)*128+c],w3=Wvs_w[(i+3)*128+c];
      #pragma unroll
      for(int q=0;q<8;q++){
        const float4 x=*(const float4*)&ns[hf*8+q][i];
        a[q]+=x.x*w0+x.y*w1+x.z*w2+x.w*w3;
      }
    }
    float bv=bvs[c];
    #pragma unroll
    for(int q=0;q<8;q++) vs[hf*8+q][c]=a[q]+bv;
  }
  __syncthreads();
  // Phase C: S1 (t<128, w_ss), S2 (t<192, w_ssg), sv (t<256, w_sv); NREC offset = t
  {
    const float* W; int col, ncol;
    if(t<128){ W=w_ss;  col=t;     ncol=128; }
    else if(t<192){ W=w_ssg; col=t-128; ncol=64; }
    else { W=w_sv;  col=t-192; ncol=64; }
    float a[16];
    #pragma unroll
    for(int q=0;q<16;q++)a[q]=0.f;
    for(int i=0;i<128;i+=4){
      float w0=W[i*ncol+col],w1=W[(i+1)*ncol+col],w2=W[(i+2)*ncol+col],w3=W[(i+3)*ncol+col];
      #pragma unroll
      for(int q=0;q<16;q++){
        const float4 x=*(const float4*)&vs[q][i];
        a[q]+=x.x*w0+x.y*w1+x.z*w2+x.w*w3;
      }
    }
    #pragma unroll
    for(int q=0;q<16;q++) NREC[(size_t)(n0+q)*1216+t]=f2b(a[q]);
  }
}

// ---------------------------------------------------------------------------
// K2: per-node vector path: NREC[256..1216) = {D1(3x128), D2(3x64), Wvs(3x64), Cn(3x64)}
// all stored as [k][col] planes. 16 nodes per block, 3125 blocks.
// ---------------------------------------------------------------------------
__global__ __launch_bounds__(256) void k2_node_vec(
  const float* __restrict__ nf,
  const float* __restrict__ Wv_v, const float* __restrict__ w_vv_s,
  const float* __restrict__ w_vvg, const float* __restrict__ w_vs, const float* __restrict__ w_vvv,
  bf16* __restrict__ NREC)
{
  __shared__ float nv[16][192];  // planes [k][v] : k*64+v
  __shared__ float vv[16][192];  // Vvn planes [k][u]
  const int t=threadIdx.x; const int n0=blockIdx.x*16;
  for(int i=t;i<16*192;i+=256){
    int nn=i/192, c=i-nn*192;      // c = v*3+k in source layout
    int v=c/3, k=c-3*v;
    nv[nn][k*64+v]=nf[(size_t)(n0+nn)*320+128+c];
  }
  __syncthreads();
  // Phase A: Vvn[k][u] = sum_v nV[k][v] * Wv_v[v*64+u]
  if(t<192){
    const int k=t>>6, u=t&63;
    float a[16];
    #pragma unroll
    for(int q=0;q<16;q++)a[q]=0.f;
    for(int v=0;v<64;v+=4){
      float w0=Wv_v[v*64+u],w1=Wv_v[(v+1)*64+u],w2=Wv_v[(v+2)*64+u],w3=Wv_v[(v+3)*64+u];
      #pragma unroll
      for(int q=0;q<16;q++){
        const float4 x=*(const float4*)&nv[q][(k<<6)+v];
        a[q]+=x.x*w0+x.y*w1+x.z*w2+x.w*w3;
      }
    }
    #pragma unroll
    for(int q=0;q<16;q++) vv[q][(k<<6)+u]=a[q];
  }
  __syncthreads();
  // Phase B: 960 outputs/node in 4 chunks of 256
  for(int cch=0;cch<4;cch++){
    int out=t+cch*256;
    if(out>=960) break;
    const float* W; int k,j,ncol,off;
    if(out<384){ k=out>>7; j=out&127; W=w_vv_s; ncol=128; off=256+(k<<7)+j; }
    else if(out<576){ int o=out-384; k=o>>6; j=o&63; W=w_vvg; ncol=64; off=640+(k<<6)+j; }
    else if(out<768){ int o=out-576; k=o>>6; j=o&63; W=w_vs;  ncol=64; off=832+(k<<6)+j; }
    else            { int o=out-768; k=o>>6; j=o&63; W=w_vvv; ncol=64; off=1024+(k<<6)+j; }
    float a[16];
    #pragma unroll
    for(int q=0;q<16;q++)a[q]=0.f;
    for(int v=0;v<64;v+=4){
      float w0=W[v*ncol+j],w1=W[(v+1)*ncol+j],w2=W[(v+2)*ncol+j],w3=W[(v+3)*ncol+j];
      #pragma unroll
      for(int q=0;q<16;q++){
        const float4 x=*(const float4*)&vv[q][(k<<6)+v];
        a[q]+=x.x*w0+x.y*w1+x.z*w2+x.w*w3;
      }
    }
    #pragma unroll
    for(int q=0;q<16;q++) NREC[(size_t)(n0+q)*1216+off]=f2b(a[q]);
  }
}

// ---------------------------------------------------------------------------
// K3: ef = edge_attr@We + be ; scores ; atomicMax into MU. 16 edges/block.
// ---------------------------------------------------------------------------
__global__ __launch_bounds__(256) void k3_scores(
  const float* __restrict__ eattr, const int* __restrict__ eidx,
  const float* __restrict__ We, const float* __restrict__ be,
  const bf16* __restrict__ Q, const bf16* __restrict__ K,
  float* __restrict__ SC, unsigned* __restrict__ MU)
{
  __shared__ float ea[16][64];
  __shared__ int ssrc[16], sdst[16];
  const int t=threadIdx.x; const int e0=blockIdx.x*16;
  for(int i=t;i<16*64;i+=256){ int nn=i>>6,c=i&63; ea[nn][c]=eattr[(size_t)(e0+nn)*64+c]; }
  if(t<16){ ssrc[t]=eidx[e0+t]; sdst[t]=eidx[NEDGE+e0+t]; }
  __syncthreads();
  float a[16];
  #pragma unroll
  for(int q=0;q<16;q++)a[q]=0.f;
  for(int i=0;i<64;i+=4){
    float w0=We[i*256+t],w1=We[(i+1)*256+t],w2=We[(i+2)*256+t],w3=We[(i+3)*256+t];
    #pragma unroll
    for(int q=0;q<16;q++){
      const float4 x=*(const float4*)&ea[q][i];
      a[q]+=x.x*w0+x.y*w1+x.z*w2+x.w*w3;
    }
  }
  const float bev=be[t];
  const int h=t>>4;
  for(int q=0;q<16;q++){
    int s=ssrc[q], d=sdst[q];
    float kv=b2f(K[(size_t)s*256+t]);
    float qv=b2f(Q[(size_t)d*256+t]);
    float v=qv*(kv+a[q]+bev);
    v=gred16(v);
    float score=v*0.25f;
    if((t&15)==0){
      SC[(size_t)(e0+q)*16+h]=score;
      atomicMax(&MU[(size_t)d*16+h], f2ord(score));
    }
  }
}

// ---------------------------------------------------------------------------
// K4: ex = exp(score - m[dst]); den += ex. one thread per (e,h).
// ---------------------------------------------------------------------------
__global__ __launch_bounds__(256) void k4_exden(
  const int* __restrict__ eidx, float* __restrict__ SC,
  const unsigned* __restrict__ MU, float* __restrict__ DEN)
{
  int tid=blockIdx.x*256+threadIdx.x;  // e*16+h
  int e=tid>>4, h=tid&15;
  int d=eidx[NEDGE+e];
  float m=ord2f(MU[(size_t)d*16+h]);
  float ex=__expf(SC[tid]-m);
  SC[tid]=ex;
  atomicAdd(&DEN[(size_t)d*16+h], ex);
}

// ---------------------------------------------------------------------------
// K6: message + LN + gates + attn + atomic aggregation. One wave per edge.
// ---------------------------------------------------------------------------
__global__ __launch_bounds__(256) void k6_message(
  const int* __restrict__ eidx, const float* __restrict__ esh,
  const bf16* __restrict__ NREC, const float* __restrict__ SC,
  const float* __restrict__ DEN,
  const float* __restrict__ b_ms, const float* __restrict__ b_mg,
  float* __restrict__ AGS, float* __restrict__ AGV)
{
  const int l = threadIdx.x & 63;
  const int e = blockIdx.x*4 + (threadIdx.x>>6);
  const int s = eidx[e], d = eidx[NEDGE+e];
  const float shs = esh[(size_t)e*4+0];
  const float sh0 = esh[(size_t)e*4+1];
  const float sh1 = esh[(size_t)e*4+2];
  const float sh2 = esh[(size_t)e*4+3];
  // attention weight = mean_h ex/den
  float av = (l<16) ? SC[(size_t)e*16+l] / DEN[(size_t)d*16+l] : 0.f;
  const float att = wred64(av) * (1.f/16.f);

  const bf16* R = NREC + (size_t)s*1216;
  const float s1a=b2f(R[l]),      s1b=b2f(R[64+l]);
  const float s2 =b2f(R[128+l]),  svv=b2f(R[192+l]);
  const float d1a0=b2f(R[256+l]),     d1a1=b2f(R[256+128+l]),  d1a2=b2f(R[256+256+l]);
  const float d1b0=b2f(R[256+64+l]),  d1b1=b2f(R[256+192+l]),  d1b2=b2f(R[256+320+l]);
  const float d20=b2f(R[640+l]),  d21=b2f(R[640+64+l]),  d22=b2f(R[640+128+l]);
  const float w0 =b2f(R[832+l]),  w1 =b2f(R[832+64+l]),  w2 =b2f(R[832+128+l]);
  const float c0 =b2f(R[1024+l]), c1 =b2f(R[1024+64+l]), c2 =b2f(R[1024+128+l]);

  float msa = shs*s1a + d1a0*sh0+d1a1*sh1+d1a2*sh2 + b_ms[l];
  float msb = shs*s1b + d1b0*sh0+d1b1*sh1+d1b2*sh2 + b_ms[64+l];
  float mgv = shs*s2  + d20*sh0 +d21*sh1 +d22*sh2  + b_mg[l];

  float sum = wred64(msa+msb+mgv);
  float sq  = wred64(msa*msa+msb*msb+mgv*mgv);
  float mean = sum*(1.f/192.f);
  float var  = sq*(1.f/192.f) - mean*mean;
  float rs   = rsqrtf(var + 1e-5f);

  // MV = sv*shv + shs*Wvs + cross(Cn, shv)
  float cr0 = c1*sh2 - c2*sh1;
  float cr1 = c2*sh0 - c0*sh2;
  float cr2 = c0*sh1 - c1*sh0;
  float mv0 = svv*sh0 + shs*w0 + cr0;
  float mv1 = svv*sh1 + shs*w1 + cr1;
  float mv2 = svv*sh2 + shs*w2 + cr2;
  float vsq = wred64(mv0*mv0+mv1*mv1+mv2*mv2);
  float vn  = rsqrtf(vsq*(1.f/64.f) + 1e-5f);

  float sga=(msa-mean)*rs, sgb=(msb-mean)*rs, sgg=(mgv-mean)*rs;
  float wV = vn * sigm(sgg) * att;
  float m0 = sga*sigm(sga)*att;
  float m1 = sgb*sigm(sgb)*att;

  atomicAdd(&AGS[(size_t)d*128+l],      m0);
  atomicAdd(&AGS[(size_t)d*128+64+l],   m1);
  atomicAdd(&AGV[(size_t)d*192+l],      mv0*wV);
  atomicAdd(&AGV[(size_t)d*192+64+l],   mv1*wV);
  atomicAdd(&AGV[(size_t)d*192+128+l],  mv2*wV);
}

// ---------------------------------------------------------------------------
// K7: final node update (residuals + 2x LN + gated FFN). 16 nodes/block.
// ---------------------------------------------------------------------------
__global__ __launch_bounds__(256) void k7_node_out(
  const float* __restrict__ nf,
  const float* __restrict__ AGS, const float* __restrict__ AGV,
  const float* __restrict__ Wo_s, const float* __restrict__ bo_s,
  const float* __restrict__ Wo_v,
  const float* __restrict__ W1_s, const float* __restrict__ b1_s,
  const float* __restrict__ W1_v,
  const float* __restrict__ W2_s, const float* __restrict__ b2_s,
  const float* __restrict__ W2_v,
  float* __restrict__ out)
{
  __shared__ float sA[16][128];   // agg_s -> silu(f[:128])
  __shared__ float sB[16][128];   // x_s -> o_s
  __shared__ float sC[16][192];   // agg_V -> f
  __shared__ float sD[16][192];   // x_V -> o_V   ([k][u] planes)
  __shared__ float sE[16][192];   // gV           ([k][u] planes)
  __shared__ float smean[16], srs[16], svn[16];
  const int t=threadIdx.x; const int n0=blockIdx.x*16;

  for(int i=t;i<16*128;i+=256){ int nn=i>>7,c=i&127; sA[nn][c]=AGS[(size_t)(n0+nn)*128+c]; }
  for(int i=t;i<16*192;i+=256){ int nn=i/192,c=i-nn*192; sC[nn][c]=AGV[(size_t)(n0+nn)*192+c]; }
  __syncthreads();

  // Phase 1: x_s = ns + agg_s@Wo_s + bo_s -> sB
  {
    const int c=t&127, hf=t>>7;
    float a[8];
    #pragma unroll
    for(int q=0;q<8;q++)a[q]=0.f;
    for(int i=0;i<128;i+=4){
      float w0=Wo_s[i*128+c],w1=Wo_s[(i+1)*128+c],w2=Wo_s[(i+2)*128+c],w3=Wo_s[(i+3)*128+c];
      #pragma unroll
      for(int q=0;q<8;q++){
        const float4 x=*(const float4*)&sA[hf*8+q][i];
        a[q]+=x.x*w0+x.y*w1+x.z*w2+x.w*w3;
      }
    }
    float bv=bo_s[c];
    #pragma unroll
    for(int q=0;q<8;q++){ int node=hf*8+q; sB[node][c]=nf[(size_t)(n0+node)*320+c]+a[q]+bv; }
  }
  // Phase 1b: x_V = nV + agg_V@Wo_v -> sD
  if(t<192){
    const int k=t>>6,u=t&63;
    float a[16];
    #pragma unroll
    for(int q=0;q<16;q++)a[q]=0.f;
    for(int v=0;v<64;v+=4){
      float w0=Wo_v[v*64+u],w1=Wo_v[(v+1)*64+u],w2=Wo_v[(v+2)*64+u],w3=Wo_v[(v+3)*64+u];
      #pragma unroll
      for(int q=0;q<16;q++){
        const float4 x=*(const float4*)&sC[q][(k<<6)+v];
        a[q]+=x.x*w0+x.y*w1+x.z*w2+x.w*w3;
      }
    }
    #pragma unroll
    for(int q=0;q<16;q++) sD[q][(k<<6)+u]=nf[(size_t)(n0+q)*320+128+u*3+k]+a[q];
  }
  __syncthreads();
  // Phase 2: LN stats
  {
    const int nn=t>>4, g=t&15;
    float sum=0,sq=0;
    #pragma unroll
    for(int j=0;j<8;j++){ float x=sB[nn][g+16*j]; sum+=x; sq+=x*x; }
    sum=gred16(sum); sq=gred16(sq);
    float mean=sum*(1.f/128.f);
    float var=sq*(1.f/128.f)-mean*mean;
    float vsq=0;
    #pragma unroll
    for(int j=0;j<12;j++){ float x=sD[nn][g+16*j]; vsq+=x*x; }
    vsq=gred16(vsq);
    if(g==0){ smean[nn]=mean; srs[nn]=rsqrtf(var+1e-5f); svn[nn]=rsqrtf(vsq*(1.f/64.f)+1e-5f); }
  }
  __syncthreads();
  for(int i=t;i<16*128;i+=256){ int nn=i>>7,c=i&127; sB[nn][c]=(sB[nn][c]-smean[nn])*srs[nn]; }
  for(int i=t;i<16*192;i+=256){ int nn=i/192,c=i-nn*192; sD[nn][c]*=svn[nn]; }
  __syncthreads();
  // Phase 3: f = x_s@W1_s + b1 -> sC
  if(t<192){
    float a[16];
    #pragma unroll
    for(int q=0;q<16;q++)a[q]=0.f;
    for(int i=0;i<128;i+=4){
      float w0=W1_s[i*192+t],w1=W1_s[(i+1)*192+t],w2=W1_s[(i+2)*192+t],w3=W1_s[(i+3)*192+t];
      #pragma unroll
      for(int q=0;q<16;q++){
        const float4 x=*(const float4*)&sB[q][i];
        a[q]+=x.x*w0+x.y*w1+x.z*w2+x.w*w3;
      }
    }
    float bv=b1_s[t];
    #pragma unroll
    for(int q=0;q<16;q++) sC[q][t]=a[q]+bv;
  }
  __syncthreads();
  // Phase 3b: gV = (x_V@W1_v)*sigmoid(f[128+u]) -> sE ; Phase 3c: silu(f[:128]) -> sA
  if(t<192){
    const int k=t>>6,u=t&63;
    float a[16];
    #pragma unroll
    for(int q=0;q<16;q++)a[q]=0.f;
    for(int v=0;v<64;v+=4){
      float w0=W1_v[v*64+u],w1=W1_v[(v+1)*64+u],w2=W1_v[(v+2)*64+u],w3=W1_v[(v+3)*64+u];
      #pragma unroll
      for(int q=0;q<16;q++){
        const float4 x=*(const float4*)&sD[q][(k<<6)+v];
        a[q]+=x.x*w0+x.y*w1+x.z*w2+x.w*w3;
      }
    }
    #pragma unroll
    for(int q=0;q<16;q++) sE[q][(k<<6)+u]=a[q]*sigm(sC[q][128+u]);
  }
  for(int i=t;i<16*128;i+=256){ int nn=i>>7,c=i&127; float x=sC[nn][c]; sA[nn][c]=x*sigm(x); }
  __syncthreads();
  // Phase 4: o_s = x_s + silu(f)@W2_s + b2 (accumulate into sB)
  {
    const int c=t&127, hf=t>>7;
    float a[8];
    #pragma unroll
    for(int q=0;q<8;q++)a[q]=0.f;
    for(int i=0;i<128;i+=4){
      float w0=W2_s[i*128+c],w1=W2_s[(i+1)*128+c],w2=W2_s[(i+2)*128+c],w3=W2_s[(i+3)*128+c];
      #pragma unroll
      for(int q=0;q<8;q++){
        const float4 x=*(const float4*)&sA[hf*8+q][i];
        a[q]+=x.x*w0+x.y*w1+x.z*w2+x.w*w3;
      }
    }
    float bv=b2_s[c];
    #pragma unroll
    for(int q=0;q<8;q++) sB[hf*8+q][c]+=a[q]+bv;
  }
  // Phase 4b: o_V = x_V + gV@W2_v (accumulate into sD)
  if(t<192){
    const int k=t>>6,u=t&63;
    float a[16];
    #pragma unroll
    for(int q=0;q<16;q++)a[q]=0.f;
    for(int v=0;v<64;v+=4){
      float w0=W2_v[v*64+u],w1=W2_v[(v+1)*64+u],w2=W2_v[(v+2)*64+u],w3=W2_v[(v+3)*64+u];
      #pragma unroll
      for(int q=0;q<16;q++){
        const float4 x=*(const float4*)&sE[q][(k<<6)+v];
        a[q]+=x.x*w0+x.y*w1+x.z*w2+x.w*w3;
      }
    }
    #pragma unroll
    for(int q=0;q<16;q++) sD[q][(k<<6)+u]+=a[q];
  }
  __syncthreads();
  // Phase 5: final LN stats
  {
    const int nn=t>>4, g=t&15;
    float sum=0,sq=0;
    #pragma unroll
    for(int j=0;j<8;j++){ float x=sB[nn][g+16*j]; sum+=x; sq+=x*x; }
    sum=gred16(sum); sq=gred16(sq);
    float mean=sum*(1.f/128.f);
    float var=sq*(1.f/128.f)-mean*mean;
    float vsq=0;
    #pragma unroll
    for(int j=0;j<12;j++){ float x=sD[nn][g+16*j]; vsq+=x*x; }
    vsq=gred16(vsq);
    if(g==0){ smean[nn]=mean; srs[nn]=rsqrtf(var+1e-5f); svn[nn]=rsqrtf(vsq*(1.f/64.f)+1e-5f); }
  }
  __syncthreads();
  for(int i=t;i<16*320;i+=256){
    int nn=i/320, c=i-nn*320;
    float v;
    if(c<128) v=(sB[nn][c]-smean[nn])*srs[nn];
    else { int j=c-128; int u=j/3, k=j-u*3; v=sD[nn][(k<<6)+u]*svn[nn]; }
    out[(size_t)(n0+nn)*320+c]=v;
  }
}

// ---------------------------------------------------------------------------
extern "C" void kernel_launch(void* const* d_in, const int* in_sizes, int n_in,
                              void* d_out, int out_size, void* d_ws, size_t ws_size,
                              hipStream_t stream)
{
  (void)in_sizes; (void)n_in; (void)out_size; (void)ws_size;
  const float* nf    =(const float*)d_in[0];
  const float* eattr =(const float*)d_in[1];
  const float* esh   =(const float*)d_in[2];
  const float* Wq    =(const float*)d_in[3];  const float* bq  =(const float*)d_in[4];
  const float* Wk    =(const float*)d_in[5];  const float* bk  =(const float*)d_in[6];
  const float* We    =(const float*)d_in[7];  const float* be  =(const float*)d_in[8];
  const float* Wv_s  =(const float*)d_in[9];  const float* bv_s=(const float*)d_in[10];
  const float* Wv_v  =(const float*)d_in[11];
  const float* w_ss  =(const float*)d_in[12]; const float* w_vv_s=(const float*)d_in[13];
  const float* w_ssg =(const float*)d_in[14]; const float* w_vvg =(const float*)d_in[15];
  const float* b_ms  =(const float*)d_in[16]; const float* b_mg  =(const float*)d_in[17];
  const float* w_sv  =(const float*)d_in[18]; const float* w_vs  =(const float*)d_in[19];
  const float* w_vvv =(const float*)d_in[20];
  const float* Wo_s  =(const float*)d_in[21]; const float* bo_s  =(const float*)d_in[22];
  const float* Wo_v  =(const float*)d_in[23];
  const float* W1_s  =(const float*)d_in[24]; const float* b1_s  =(const float*)d_in[25];
  const float* W1_v  =(const float*)d_in[26];
  const float* W2_s  =(const float*)d_in[27]; const float* b2_s  =(const float*)d_in[28];
  const float* W2_v  =(const float*)d_in[29];
  const int*   eidx  =(const int*)d_in[30];
  float* out=(float*)d_out;

  char* w=(char*)d_ws;
  bf16* Q    =(bf16*)w;  w+=(size_t)NNODE*256*2;
  bf16* Kb   =(bf16*)w;  w+=(size_t)NNODE*256*2;
  bf16* NREC =(bf16*)w;  w+=(size_t)NNODE*1216*2;
  float* SC  =(float*)w; w+=(size_t)NEDGE*16*4;
  unsigned* MU=(unsigned*)w; w+=(size_t)NNODE*16*4;
  float* DEN =(float*)w; w+=(size_t)NNODE*16*4;
  float* AGS =(float*)w; w+=(size_t)NNODE*128*4;
  float* AGV =(float*)w; w+=(size_t)NNODE*192*4;

  hipMemsetAsync(MU, 0,(size_t)NNODE*16*4, stream);
  hipMemsetAsync(DEN,0,(size_t)NNODE*16*4, stream);
  hipMemsetAsync(AGS,0,(size_t)NNODE*128*4,stream);
  hipMemsetAsync(AGV,0,(size_t)NNODE*192*4,stream);

  k1_node_scalar<<<NNODE/16,256,0,stream>>>(nf,Wq,bq,Wk,bk,Wv_s,bv_s,w_ss,w_ssg,w_sv,Q,Kb,NREC);
  k2_node_vec   <<<NNODE/16,256,0,stream>>>(nf,Wv_v,w_vv_s,w_vvg,w_vs,w_vvv,NREC);
  k3_scores     <<<NEDGE/16,256,0,stream>>>(eattr,eidx,We,be,Q,Kb,SC,MU);
  k4_exden      <<<(NEDGE*16)/256,256,0,stream>>>(eidx,SC,MU,DEN);
  k6_message    <<<NEDGE/4,256,0,stream>>>(eidx,esh,NREC,SC,DEN,b_ms,b_mg,AGS,AGV);
  k7_node_out   <<<NNODE/16,256,0,stream>>>(nf,AGS,AGV,Wo_s,bo_s,Wo_v,W1_s,b1_s,W1_v,W2_s,b2_s,W2_v,out);
}

// Round 3
// 1295.297 us; speedup vs baseline: 1.0629x; 1.0629x over previous
//
#include <hip/hip_runtime.h>
#include <hip/hip_bf16.h>

#define NNODE 50000
#define NEDGE 250000

typedef __hip_bfloat16 bf16;

__device__ __forceinline__ float b2f(bf16 x){ return __bfloat162float(x); }
__device__ __forceinline__ bf16  f2b(float x){ return __float2bfloat16(x); }
__device__ __forceinline__ float sigm(float x){ return 1.0f/(1.0f+__expf(-x)); }
__device__ __forceinline__ float wred64(float v){
  #pragma unroll
  for(int o=32;o>0;o>>=1) v+=__shfl_xor(v,o,64);
  return v;
}
__device__ __forceinline__ float gred16(float v){
  v+=__shfl_xor(v,1,64); v+=__shfl_xor(v,2,64); v+=__shfl_xor(v,4,64); v+=__shfl_xor(v,8,64);
  return v;
}

// ---------------------------------------------------------------------------
// K1: per-node scalar path: Q,K (bf16) and NREC[0..256) = {S1(128), S2(64), sv(64)}
// ---------------------------------------------------------------------------
__global__ __launch_bounds__(256) void k1_node_scalar(
  const float* __restrict__ nf,
  const float* __restrict__ Wq, const float* __restrict__ bq,
  const float* __restrict__ Wk, const float* __restrict__ bk,
  const float* __restrict__ Wvs_w, const float* __restrict__ bvs,
  const float* __restrict__ w_ss, const float* __restrict__ w_ssg, const float* __restrict__ w_sv,
  bf16* __restrict__ Q, bf16* __restrict__ K, bf16* __restrict__ NREC)
{
  __shared__ float ns[16][128];
  __shared__ float vs[16][128];
  const int t = threadIdx.x;
  const int n0 = blockIdx.x * 16;
  for(int i=t;i<16*128;i+=256){ int nn=i>>7, c=i&127; ns[nn][c]=nf[(size_t)(n0+nn)*320+c]; }
  __syncthreads();
  {
    float aq[16], ak[16];
    #pragma unroll
    for(int q=0;q<16;q++){aq[q]=0.f;ak[q]=0.f;}
    for(int i=0;i<128;i+=4){
      float wq0=Wq[i*256+t],wq1=Wq[(i+1)*256+t],wq2=Wq[(i+2)*256+t],wq3=Wq[(i+3)*256+t];
      float wk0=Wk[i*256+t],wk1=Wk[(i+1)*256+t],wk2=Wk[(i+2)*256+t],wk3=Wk[(i+3)*256+t];
      #pragma unroll
      for(int q=0;q<16;q++){
        const float4 x=*(const float4*)&ns[q][i];
        aq[q]+=x.x*wq0+x.y*wq1+x.z*wq2+x.w*wq3;
        ak[q]+=x.x*wk0+x.y*wk1+x.z*wk2+x.w*wk3;
      }
    }
    float bqv=bq[t], bkv=bk[t];
    #pragma unroll
    for(int q=0;q<16;q++){
      Q[(size_t)(n0+q)*256+t]=f2b(aq[q]+bqv);
      K[(size_t)(n0+q)*256+t]=f2b(ak[q]+bkv);
    }
  }
  {
    const int c=t&127, hf=t>>7;
    float a[8];
    #pragma unroll
    for(int q=0;q<8;q++)a[q]=0.f;
    for(int i=0;i<128;i+=4){
      float w0=Wvs_w[i*128+c],w1=Wvs_w[(i+1)*128+c],w2=Wvs_w[(i+2)*128+c],w3=Wvs_w[(i+3)*128+c];
      #pragma unroll
      for(int q=0;q<8;q++){
        const float4 x=*(const float4*)&ns[hf*8+q][i];
        a[q]+=x.x*w0+x.y*w1+x.z*w2+x.w*w3;
      }
    }
    float bv=bvs[c];
    #pragma unroll
    for(int q=0;q<8;q++) vs[hf*8+q][c]=a[q]+bv;
  }
  __syncthreads();
  {
    const float* W; int col, ncol;
    if(t<128){ W=w_ss;  col=t;     ncol=128; }
    else if(t<192){ W=w_ssg; col=t-128; ncol=64; }
    else { W=w_sv;  col=t-192; ncol=64; }
    float a[16];
    #pragma unroll
    for(int q=0;q<16;q++)a[q]=0.f;
    for(int i=0;i<128;i+=4){
      float w0=W[i*ncol+col],w1=W[(i+1)*ncol+col],w2=W[(i+2)*ncol+col],w3=W[(i+3)*ncol+col];
      #pragma unroll
      for(int q=0;q<16;q++){
        const float4 x=*(const float4*)&vs[q][i];
        a[q]+=x.x*w0+x.y*w1+x.z*w2+x.w*w3;
      }
    }
    #pragma unroll
    for(int q=0;q<16;q++) NREC[(size_t)(n0+q)*1216+t]=f2b(a[q]);
  }
}

// ---------------------------------------------------------------------------
// K2: per-node vector path: NREC[256..1216) = {D1(3x128), D2(3x64), Wvs(3x64), Cn(3x64)}
// ---------------------------------------------------------------------------
__global__ __launch_bounds__(256) void k2_node_vec(
  const float* __restrict__ nf,
  const float* __restrict__ Wv_v, const float* __restrict__ w_vv_s,
  const float* __restrict__ w_vvg, const float* __restrict__ w_vs, const float* __restrict__ w_vvv,
  bf16* __restrict__ NREC)
{
  __shared__ float nv[16][192];
  __shared__ float vv[16][192];
  const int t=threadIdx.x; const int n0=blockIdx.x*16;
  for(int i=t;i<16*192;i+=256){
    int nn=i/192, c=i-nn*192;
    int v=c/3, k=c-3*v;
    nv[nn][k*64+v]=nf[(size_t)(n0+nn)*320+128+c];
  }
  __syncthreads();
  if(t<192){
    const int k=t>>6, u=t&63;
    float a[16];
    #pragma unroll
    for(int q=0;q<16;q++)a[q]=0.f;
    for(int v=0;v<64;v+=4){
      float w0=Wv_v[v*64+u],w1=Wv_v[(v+1)*64+u],w2=Wv_v[(v+2)*64+u],w3=Wv_v[(v+3)*64+u];
      #pragma unroll
      for(int q=0;q<16;q++){
        const float4 x=*(const float4*)&nv[q][(k<<6)+v];
        a[q]+=x.x*w0+x.y*w1+x.z*w2+x.w*w3;
      }
    }
    #pragma unroll
    for(int q=0;q<16;q++) vv[q][(k<<6)+u]=a[q];
  }
  __syncthreads();
  for(int cch=0;cch<4;cch++){
    int out=t+cch*256;
    if(out>=960) break;
    const float* W; int k,j,ncol,off;
    if(out<384){ k=out>>7; j=out&127; W=w_vv_s; ncol=128; off=256+(k<<7)+j; }
    else if(out<576){ int o=out-384; k=o>>6; j=o&63; W=w_vvg; ncol=64; off=640+(k<<6)+j; }
    else if(out<768){ int o=out-576; k=o>>6; j=o&63; W=w_vs;  ncol=64; off=832+(k<<6)+j; }
    else            { int o=out-768; k=o>>6; j=o&63; W=w_vvv; ncol=64; off=1024+(k<<6)+j; }
    float a[16];
    #pragma unroll
    for(int q=0;q<16;q++)a[q]=0.f;
    for(int v=0;v<64;v+=4){
      float w0=W[v*ncol+j],w1=W[(v+1)*ncol+j],w2=W[(v+2)*ncol+j],w3=W[(v+3)*ncol+j];
      #pragma unroll
      for(int q=0;q<16;q++){
        const float4 x=*(const float4*)&vv[q][(k<<6)+v];
        a[q]+=x.x*w0+x.y*w1+x.z*w2+x.w*w3;
      }
    }
    #pragma unroll
    for(int q=0;q<16;q++) NREC[(size_t)(n0+q)*1216+off]=f2b(a[q]);
  }
}

// ---------------------------------------------------------------------------
// Sort-by-dst (counting sort): histogram -> scan -> scatter
// ---------------------------------------------------------------------------
__global__ __launch_bounds__(256) void k_hist(const int* __restrict__ eidx, int* __restrict__ counts){
  int e=blockIdx.x*256+threadIdx.x;
  if(e<NEDGE) atomicAdd(&counts[eidx[NEDGE+e]],1);
}

__global__ __launch_bounds__(1024) void k_scan(const int* __restrict__ counts, int* __restrict__ off, int* __restrict__ cursor){
  __shared__ int wsum[16];
  __shared__ int woff[17];
  __shared__ int carry_s;
  const int t=threadIdx.x, ln=t&63, wid=t>>6;
  if(t==0) carry_s=0;
  __syncthreads();
  for(int base=0;base<NNODE;base+=1024){
    int idx=base+t;
    int v=(idx<NNODE)?counts[idx]:0;
    int incl=v;
    #pragma unroll
    for(int o=1;o<64;o<<=1){ int x=__shfl_up(incl,o,64); if(ln>=o) incl+=x; }
    if(ln==63) wsum[wid]=incl;
    __syncthreads();
    if(t<16){
      int s=wsum[t];
      #pragma unroll
      for(int o=1;o<16;o<<=1){ int x=__shfl_up(s,o,64); if(t>=o) s+=x; }
      woff[t+1]=s;
      if(t==0) woff[0]=0;
    }
    __syncthreads();
    int excl=carry_s+woff[wid]+(incl-v);
    if(idx<NNODE){ off[idx]=excl; cursor[idx]=excl; }
    __syncthreads();
    if(t==0) carry_s+=woff[16];
    __syncthreads();
  }
  if(t==0) off[NNODE]=NEDGE;
}

__global__ __launch_bounds__(256) void k_scatter(const int* __restrict__ eidx, int* __restrict__ cursor, int* __restrict__ eord){
  int e=blockIdx.x*256+threadIdx.x;
  if(e<NEDGE){
    int d=eidx[NEDGE+e];
    int pos=atomicAdd(&cursor[d],1);
    eord[pos]=e;
  }
}

// ---------------------------------------------------------------------------
// K3: ef = edge_attr@We + be ; raw scores -> SC. 16 edges/block.
// ---------------------------------------------------------------------------
__global__ __launch_bounds__(256) void k3_scores(
  const float* __restrict__ eattr, const int* __restrict__ eidx,
  const float* __restrict__ We, const float* __restrict__ be,
  const bf16* __restrict__ Q, const bf16* __restrict__ K,
  float* __restrict__ SC)
{
  __shared__ float ea[16][64];
  __shared__ int ssrc[16], sdst[16];
  const int t=threadIdx.x; const int e0=blockIdx.x*16;
  for(int i=t;i<16*64;i+=256){ int nn=i>>6,c=i&63; ea[nn][c]=eattr[(size_t)(e0+nn)*64+c]; }
  if(t<16){ ssrc[t]=eidx[e0+t]; sdst[t]=eidx[NEDGE+e0+t]; }
  __syncthreads();
  float a[16];
  #pragma unroll
  for(int q=0;q<16;q++)a[q]=0.f;
  for(int i=0;i<64;i+=4){
    float w0=We[i*256+t],w1=We[(i+1)*256+t],w2=We[(i+2)*256+t],w3=We[(i+3)*256+t];
    #pragma unroll
    for(int q=0;q<16;q++){
      const float4 x=*(const float4*)&ea[q][i];
      a[q]+=x.x*w0+x.y*w1+x.z*w2+x.w*w3;
    }
  }
  const float bev=be[t];
  const int h=t>>4;
  for(int q=0;q<16;q++){
    int s=ssrc[q], d=sdst[q];
    float kv=b2f(K[(size_t)s*256+t]);
    float qv=b2f(Q[(size_t)d*256+t]);
    float v=qv*(kv+a[q]+bev);
    v=gred16(v);
    if((t&15)==0) SC[(size_t)(e0+q)*16+h]=v*0.25f;
  }
}

// ---------------------------------------------------------------------------
// K6: per-dst-node aggregation. One wave per node, 4 nodes/block. No atomics.
// ---------------------------------------------------------------------------
__global__ __launch_bounds__(256) void k6_agg(
  const int* __restrict__ eidx, const float* __restrict__ esh,
  const bf16* __restrict__ NREC, const float* __restrict__ SC,
  const int* __restrict__ OFF, const int* __restrict__ EORD,
  const float* __restrict__ b_ms, const float* __restrict__ b_mg,
  float* __restrict__ AGS, float* __restrict__ AGV)
{
  const int l = threadIdx.x & 63;
  const int n = blockIdx.x*4 + (threadIdx.x>>6);
  const int beg=OFF[n], end=OFF[n+1];
  const float bmsa=b_ms[l], bmsb=b_ms[64+l], bmgv=b_mg[l];

  // softmax stats (lanes 0..15 hold head h=l)
  float mh=-1e30f;
  for(int i=beg;i<end;i++){
    int e=EORD[i];
    if(l<16) mh=fmaxf(mh, SC[(size_t)e*16+l]);
  }
  float dh=0.f;
  for(int i=beg;i<end;i++){
    int e=EORD[i];
    if(l<16) dh+=__expf(SC[(size_t)e*16+l]-mh);
  }
  float rdh = (end>beg && l<16) ? 1.f/dh : 0.f;

  float as0=0.f,as1=0.f,av0acc=0.f,av1acc=0.f,av2acc=0.f;
  for(int i=beg;i<end;i++){
    const int e=EORD[i];
    const int s=eidx[e];
    const float4 sh4=*(const float4*)&esh[(size_t)e*4];
    const float shs=sh4.x, sh0=sh4.y, sh1=sh4.z, sh2=sh4.w;
    float av=(l<16)? __expf(SC[(size_t)e*16+l]-mh)*rdh : 0.f;
    const float att=wred64(av)*(1.f/16.f);

    const bf16* R = NREC + (size_t)s*1216;
    const float s1a=b2f(R[l]),      s1b=b2f(R[64+l]);
    const float s2 =b2f(R[128+l]),  svv=b2f(R[192+l]);
    const float d1a0=b2f(R[256+l]),     d1a1=b2f(R[256+128+l]),  d1a2=b2f(R[256+256+l]);
    const float d1b0=b2f(R[256+64+l]),  d1b1=b2f(R[256+192+l]),  d1b2=b2f(R[256+320+l]);
    const float d20=b2f(R[640+l]),  d21=b2f(R[640+64+l]),  d22=b2f(R[640+128+l]);
    const float w0 =b2f(R[832+l]),  w1 =b2f(R[832+64+l]),  w2 =b2f(R[832+128+l]);
    const float c0 =b2f(R[1024+l]), c1 =b2f(R[1024+64+l]), c2 =b2f(R[1024+128+l]);

    float msa = shs*s1a + d1a0*sh0+d1a1*sh1+d1a2*sh2 + bmsa;
    float msb = shs*s1b + d1b0*sh0+d1b1*sh1+d1b2*sh2 + bmsb;
    float mgv = shs*s2  + d20*sh0 +d21*sh1 +d22*sh2  + bmgv;

    float sum = wred64(msa+msb+mgv);
    float sq  = wred64(msa*msa+msb*msb+mgv*mgv);
    float mean = sum*(1.f/192.f);
    float var  = sq*(1.f/192.f) - mean*mean;
    float rs   = rsqrtf(var + 1e-5f);

    float cr0 = c1*sh2 - c2*sh1;
    float cr1 = c2*sh0 - c0*sh2;
    float cr2 = c0*sh1 - c1*sh0;
    float mv0 = svv*sh0 + shs*w0 + cr0;
    float mv1 = svv*sh1 + shs*w1 + cr1;
    float mv2 = svv*sh2 + shs*w2 + cr2;
    float vsq = wred64(mv0*mv0+mv1*mv1+mv2*mv2);
    float vn  = rsqrtf(vsq*(1.f/64.f) + 1e-5f);

    float sga=(msa-mean)*rs, sgb=(msb-mean)*rs, sgg=(mgv-mean)*rs;
    float wV = vn * sigm(sgg) * att;
    as0 += sga*sigm(sga)*att;
    as1 += sgb*sigm(sgb)*att;
    av0acc += mv0*wV;
    av1acc += mv1*wV;
    av2acc += mv2*wV;
  }
  AGS[(size_t)n*128+l]     =as0;
  AGS[(size_t)n*128+64+l]  =as1;
  AGV[(size_t)n*192+l]     =av0acc;
  AGV[(size_t)n*192+64+l]  =av1acc;
  AGV[(size_t)n*192+128+l] =av2acc;
}

// ---------------------------------------------------------------------------
// K7: final node update (residuals + 2x LN + gated FFN). 16 nodes/block.
// ---------------------------------------------------------------------------
__global__ __launch_bounds__(256) void k7_node_out(
  const float* __restrict__ nf,
  const float* __restrict__ AGS, const float* __restrict__ AGV,
  const float* __restrict__ Wo_s, const float* __restrict__ bo_s,
  const float* __restrict__ Wo_v,
  const float* __restrict__ W1_s, const float* __restrict__ b1_s,
  const float* __restrict__ W1_v,
  const float* __restrict__ W2_s, const float* __restrict__ b2_s,
  const float* __restrict__ W2_v,
  float* __restrict__ out)
{
  __shared__ float sA[16][128];
  __shared__ float sB[16][128];
  __shared__ float sC[16][192];
  __shared__ float sD[16][192];
  __shared__ float sE[16][192];
  __shared__ float smean[16], srs[16], svn[16];
  const int t=threadIdx.x; const int n0=blockIdx.x*16;

  for(int i=t;i<16*128;i+=256){ int nn=i>>7,c=i&127; sA[nn][c]=AGS[(size_t)(n0+nn)*128+c]; }
  for(int i=t;i<16*192;i+=256){ int nn=i/192,c=i-nn*192; sC[nn][c]=AGV[(size_t)(n0+nn)*192+c]; }
  __syncthreads();

  {
    const int c=t&127, hf=t>>7;
    float a[8];
    #pragma unroll
    for(int q=0;q<8;q++)a[q]=0.f;
    for(int i=0;i<128;i+=4){
      float w0=Wo_s[i*128+c],w1=Wo_s[(i+1)*128+c],w2=Wo_s[(i+2)*128+c],w3=Wo_s[(i+3)*128+c];
      #pragma unroll
      for(int q=0;q<8;q++){
        const float4 x=*(const float4*)&sA[hf*8+q][i];
        a[q]+=x.x*w0+x.y*w1+x.z*w2+x.w*w3;
      }
    }
    float bv=bo_s[c];
    #pragma unroll
    for(int q=0;q<8;q++){ int node=hf*8+q; sB[node][c]=nf[(size_t)(n0+node)*320+c]+a[q]+bv; }
  }
  if(t<192){
    const int k=t>>6,u=t&63;
    float a[16];
    #pragma unroll
    for(int q=0;q<16;q++)a[q]=0.f;
    for(int v=0;v<64;v+=4){
      float w0=Wo_v[v*64+u],w1=Wo_v[(v+1)*64+u],w2=Wo_v[(v+2)*64+u],w3=Wo_v[(v+3)*64+u];
      #pragma unroll
      for(int q=0;q<16;q++){
        const float4 x=*(const float4*)&sC[q][(k<<6)+v];
        a[q]+=x.x*w0+x.y*w1+x.z*w2+x.w*w3;
      }
    }
    #pragma unroll
    for(int q=0;q<16;q++) sD[q][(k<<6)+u]=nf[(size_t)(n0+q)*320+128+u*3+k]+a[q];
  }
  __syncthreads();
  {
    const int nn=t>>4, g=t&15;
    float sum=0,sq=0;
    #pragma unroll
    for(int j=0;j<8;j++){ float x=sB[nn][g+16*j]; sum+=x; sq+=x*x; }
    sum=gred16(sum); sq=gred16(sq);
    float mean=sum*(1.f/128.f);
    float var=sq*(1.f/128.f)-mean*mean;
    float vsq=0;
    #pragma unroll
    for(int j=0;j<12;j++){ float x=sD[nn][g+16*j]; vsq+=x*x; }
    vsq=gred16(vsq);
    if(g==0){ smean[nn]=mean; srs[nn]=rsqrtf(var+1e-5f); svn[nn]=rsqrtf(vsq*(1.f/64.f)+1e-5f); }
  }
  __syncthreads();
  for(int i=t;i<16*128;i+=256){ int nn=i>>7,c=i&127; sB[nn][c]=(sB[nn][c]-smean[nn])*srs[nn]; }
  for(int i=t;i<16*192;i+=256){ int nn=i/192,c=i-nn*192; sD[nn][c]*=svn[nn]; }
  __syncthreads();
  if(t<192){
    float a[16];
    #pragma unroll
    for(int q=0;q<16;q++)a[q]=0.f;
    for(int i=0;i<128;i+=4){
      float w0=W1_s[i*192+t],w1=W1_s[(i+1)*192+t],w2=W1_s[(i+2)*192+t],w3=W1_s[(i+3)*192+t];
      #pragma unroll
      for(int q=0;q<16;q++){
        const float4 x=*(const float4*)&sB[q][i];
        a[q]+=x.x*w0+x.y*w1+x.z*w2+x.w*w3;
      }
    }
    float bv=b1_s[t];
    #pragma unroll
    for(int q=0;q<16;q++) sC[q][t]=a[q]+bv;
  }
  __syncthreads();
  if(t<192){
    const int k=t>>6,u=t&63;
    float a[16];
    #pragma unroll
    for(int q=0;q<16;q++)a[q]=0.f;
    for(int v=0;v<64;v+=4){
      float w0=W1_v[v*64+u],w1=W1_v[(v+1)*64+u],w2=W1_v[(v+2)*64+u],w3=W1_v[(v+3)*64+u];
      #pragma unroll
      for(int q=0;q<16;q++){
        const float4 x=*(const float4*)&sD[q][(k<<6)+v];
        a[q]+=x.x*w0+x.y*w1+x.z*w2+x.w*w3;
      }
    }
    #pragma unroll
    for(int q=0;q<16;q++) sE[q][(k<<6)+u]=a[q]*sigm(sC[q][128+u]);
  }
  for(int i=t;i<16*128;i+=256){ int nn=i>>7,c=i&127; float x=sC[nn][c]; sA[nn][c]=x*sigm(x); }
  __syncthreads();
  {
    const int c=t&127, hf=t>>7;
    float a[8];
    #pragma unroll
    for(int q=0;q<8;q++)a[q]=0.f;
    for(int i=0;i<128;i+=4){
      float w0=W2_s[i*128+c],w1=W2_s[(i+1)*128+c],w2=W2_s[(i+2)*128+c],w3=W2_s[(i+3)*128+c];
      #pragma unroll
      for(int q=0;q<8;q++){
        const float4 x=*(const float4*)&sA[hf*8+q][i];
        a[q]+=x.x*w0+x.y*w1+x.z*w2+x.w*w3;
      }
    }
    float bv=b2_s[c];
    #pragma unroll
    for(int q=0;q<8;q++) sB[hf*8+q][c]+=a[q]+bv;
  }
  if(t<192){
    const int k=t>>6,u=t&63;
    float a[16];
    #pragma unroll
    for(int q=0;q<16;q++)a[q]=0.f;
    for(int v=0;v<64;v+=4){
      float w0=W2_v[v*64+u],w1=W2_v[(v+1)*64+u],w2=W2_v[(v+2)*64+u],w3=W2_v[(v+3)*64+u];
      #pragma unroll
      for(int q=0;q<16;q++){
        const float4 x=*(const float4*)&sE[q][(k<<6)+v];
        a[q]+=x.x*w0+x.y*w1+x.z*w2+x.w*w3;
      }
    }
    #pragma unroll
    for(int q=0;q<16;q++) sD[q][(k<<6)+u]+=a[q];
  }
  __syncthreads();
  {
    const int nn=t>>4, g=t&15;
    float sum=0,sq=0;
    #pragma unroll
    for(int j=0;j<8;j++){ float x=sB[nn][g+16*j]; sum+=x; sq+=x*x; }
    sum=gred16(sum); sq=gred16(sq);
    float mean=sum*(1.f/128.f);
    float var=sq*(1.f/128.f)-mean*mean;
    float vsq=0;
    #pragma unroll
    for(int j=0;j<12;j++){ float x=sD[nn][g+16*j]; vsq+=x*x; }
    vsq=gred16(vsq);
    if(g==0){ smean[nn]=mean; srs[nn]=rsqrtf(var+1e-5f); svn[nn]=rsqrtf(vsq*(1.f/64.f)+1e-5f); }
  }
  __syncthreads();
  for(int i=t;i<16*320;i+=256){
    int nn=i/320, c=i-nn*320;
    float v;
    if(c<128) v=(sB[nn][c]-smean[nn])*srs[nn];
    else { int j=c-128; int u=j/3, k=j-u*3; v=sD[nn][(k<<6)+u]*svn[nn]; }
    out[(size_t)(n0+nn)*320+c]=v;
  }
}

// ---------------------------------------------------------------------------
extern "C" void kernel_launch(void* const* d_in, const int* in_sizes, int n_in,
                              void* d_out, int out_size, void* d_ws, size_t ws_size,
                              hipStream_t stream)
{
  (void)in_sizes; (void)n_in; (void)out_size; (void)ws_size;
  const float* nf    =(const float*)d_in[0];
  const float* eattr =(const float*)d_in[1];
  const float* esh   =(const float*)d_in[2];
  const float* Wq    =(const float*)d_in[3];  const float* bq  =(const float*)d_in[4];
  const float* Wk    =(const float*)d_in[5];  const float* bk  =(const float*)d_in[6];
  const float* We    =(const float*)d_in[7];  const float* be  =(const float*)d_in[8];
  const float* Wv_s  =(const float*)d_in[9];  const float* bv_s=(const float*)d_in[10];
  const float* Wv_v  =(const float*)d_in[11];
  const float* w_ss  =(const float*)d_in[12]; const float* w_vv_s=(const float*)d_in[13];
  const float* w_ssg =(const float*)d_in[14]; const float* w_vvg =(const float*)d_in[15];
  const float* b_ms  =(const float*)d_in[16]; const float* b_mg  =(const float*)d_in[17];
  const float* w_sv  =(const float*)d_in[18]; const float* w_vs  =(const float*)d_in[19];
  const float* w_vvv =(const float*)d_in[20];
  const float* Wo_s  =(const float*)d_in[21]; const float* bo_s  =(const float*)d_in[22];
  const float* Wo_v  =(const float*)d_in[23];
  const float* W1_s  =(const float*)d_in[24]; const float* b1_s  =(const float*)d_in[25];
  const float* W1_v  =(const float*)d_in[26];
  const float* W2_s  =(const float*)d_in[27]; const float* b2_s  =(const float*)d_in[28];
  const float* W2_v  =(const float*)d_in[29];
  const int*   eidx  =(const int*)d_in[30];
  float* out=(float*)d_out;

  char* w=(char*)d_ws;
  bf16* Q    =(bf16*)w;  w+=(size_t)NNODE*256*2;
  bf16* Kb   =(bf16*)w;  w+=(size_t)NNODE*256*2;
  bf16* NREC =(bf16*)w;  w+=(size_t)NNODE*1216*2;
  float* SC  =(float*)w; w+=(size_t)NEDGE*16*4;
  float* AGS =(float*)w; w+=(size_t)NNODE*128*4;
  float* AGV =(float*)w; w+=(size_t)NNODE*192*4;
  int* COUNTS=(int*)w;   w+=(size_t)NNODE*4;
  int* OFFb  =(int*)w;   w+=(size_t)(NNODE+1)*4;
  int* CURSOR=(int*)w;   w+=(size_t)NNODE*4;
  int* EORDb =(int*)w;   w+=(size_t)NEDGE*4;

  hipMemsetAsync(COUNTS,0,(size_t)NNODE*4,stream);

  k_hist        <<<(NEDGE+255)/256,256,0,stream>>>(eidx,COUNTS);
  k_scan        <<<1,1024,0,stream>>>(COUNTS,OFFb,CURSOR);
  k_scatter     <<<(NEDGE+255)/256,256,0,stream>>>(eidx,CURSOR,EORDb);
  k1_node_scalar<<<NNODE/16,256,0,stream>>>(nf,Wq,bq,Wk,bk,Wv_s,bv_s,w_ss,w_ssg,w_sv,Q,Kb,NREC);
  k2_node_vec   <<<NNODE/16,256,0,stream>>>(nf,Wv_v,w_vv_s,w_vvg,w_vs,w_vvv,NREC);
  k3_scores     <<<NEDGE/16,256,0,stream>>>(eattr,eidx,We,be,Q,Kb,SC);
  k6_agg        <<<NNODE/4,256,0,stream>>>(eidx,esh,NREC,SC,OFFb,EORDb,b_ms,b_mg,AGS,AGV);
  k7_node_out   <<<NNODE/16,256,0,stream>>>(nf,AGS,AGV,Wo_s,bo_s,Wo_v,W1_s,b1_s,W1_v,W2_s,b2_s,W2_v,out);
}

// Round 4
// 1099.837 us; speedup vs baseline: 1.2518x; 1.1777x over previous
//
#include <hip/hip_runtime.h>
#include <hip/hip_bf16.h>

#define NNODE 50000
#define NEDGE 250000

typedef __hip_bfloat16 bf16;
typedef __attribute__((ext_vector_type(8))) short short8v;
typedef __attribute__((ext_vector_type(4))) float f32x4;

__device__ __forceinline__ float b2f(bf16 x){ return __bfloat162float(x); }
__device__ __forceinline__ bf16  f2b(float x){ return __float2bfloat16(x); }
__device__ __forceinline__ short f2s(float x){ bf16 h=f2b(x); short s; __builtin_memcpy(&s,&h,2); return s; }
__device__ __forceinline__ float sigm(float x){ return 1.0f/(1.0f+__expf(-x)); }
__device__ __forceinline__ float wred64(float v){
  #pragma unroll
  for(int o=32;o>0;o>>=1) v+=__shfl_xor(v,o,64);
  return v;
}
__device__ __forceinline__ float gred16(float v){
  v+=__shfl_xor(v,1,64); v+=__shfl_xor(v,2,64); v+=__shfl_xor(v,4,64); v+=__shfl_xor(v,8,64);
  return v;
}

// ---------------------------------------------------------------------------
// K1: per-node scalar path: Q,K (bf16) and NREC[0..256) = {S1(128), S2(64), sv(64)}
// ---------------------------------------------------------------------------
__global__ __launch_bounds__(256) void k1_node_scalar(
  const float* __restrict__ nf,
  const float* __restrict__ Wq, const float* __restrict__ bq,
  const float* __restrict__ Wk, const float* __restrict__ bk,
  const float* __restrict__ Wvs_w, const float* __restrict__ bvs,
  const float* __restrict__ w_ss, const float* __restrict__ w_ssg, const float* __restrict__ w_sv,
  bf16* __restrict__ Q, bf16* __restrict__ K, bf16* __restrict__ NREC)
{
  __shared__ float ns[16][128];
  __shared__ float vs[16][128];
  const int t = threadIdx.x;
  const int n0 = blockIdx.x * 16;
  for(int i=t;i<16*128;i+=256){ int nn=i>>7, c=i&127; ns[nn][c]=nf[(size_t)(n0+nn)*320+c]; }
  __syncthreads();
  {
    float aq[16], ak[16];
    #pragma unroll
    for(int q=0;q<16;q++){aq[q]=0.f;ak[q]=0.f;}
    for(int i=0;i<128;i+=4){
      float wq0=Wq[i*256+t],wq1=Wq[(i+1)*256+t],wq2=Wq[(i+2)*256+t],wq3=Wq[(i+3)*256+t];
      float wk0=Wk[i*256+t],wk1=Wk[(i+1)*256+t],wk2=Wk[(i+2)*256+t],wk3=Wk[(i+3)*256+t];
      #pragma unroll
      for(int q=0;q<16;q++){
        const float4 x=*(const float4*)&ns[q][i];
        aq[q]+=x.x*wq0+x.y*wq1+x.z*wq2+x.w*wq3;
        ak[q]+=x.x*wk0+x.y*wk1+x.z*wk2+x.w*wk3;
      }
    }
    float bqv=bq[t], bkv=bk[t];
    #pragma unroll
    for(int q=0;q<16;q++){
      Q[(size_t)(n0+q)*256+t]=f2b(aq[q]+bqv);
      K[(size_t)(n0+q)*256+t]=f2b(ak[q]+bkv);
    }
  }
  {
    const int c=t&127, hf=t>>7;
    float a[8];
    #pragma unroll
    for(int q=0;q<8;q++)a[q]=0.f;
    for(int i=0;i<128;i+=4){
      float w0=Wvs_w[i*128+c],w1=Wvs_w[(i+1)*128+c],w2=Wvs_w[(i+2)*128+c],w3=Wvs_w[(i+3)*128+c];
      #pragma unroll
      for(int q=0;q<8;q++){
        const float4 x=*(const float4*)&ns[hf*8+q][i];
        a[q]+=x.x*w0+x.y*w1+x.z*w2+x.w*w3;
      }
    }
    float bv=bvs[c];
    #pragma unroll
    for(int q=0;q<8;q++) vs[hf*8+q][c]=a[q]+bv;
  }
  __syncthreads();
  {
    const float* W; int col, ncol;
    if(t<128){ W=w_ss;  col=t;     ncol=128; }
    else if(t<192){ W=w_ssg; col=t-128; ncol=64; }
    else { W=w_sv;  col=t-192; ncol=64; }
    float a[16];
    #pragma unroll
    for(int q=0;q<16;q++)a[q]=0.f;
    for(int i=0;i<128;i+=4){
      float w0=W[i*ncol+col],w1=W[(i+1)*ncol+col],w2=W[(i+2)*ncol+col],w3=W[(i+3)*ncol+col];
      #pragma unroll
      for(int q=0;q<16;q++){
        const float4 x=*(const float4*)&vs[q][i];
        a[q]+=x.x*w0+x.y*w1+x.z*w2+x.w*w3;
      }
    }
    #pragma unroll
    for(int q=0;q<16;q++) NREC[(size_t)(n0+q)*1216+t]=f2b(a[q]);
  }
}

// ---------------------------------------------------------------------------
// K2: per-node vector path: NREC[256..1216) = {D1(3x128), D2(3x64), Wvs(3x64), Cn(3x64)}
// ---------------------------------------------------------------------------
__global__ __launch_bounds__(256) void k2_node_vec(
  const float* __restrict__ nf,
  const float* __restrict__ Wv_v, const float* __restrict__ w_vv_s,
  const float* __restrict__ w_vvg, const float* __restrict__ w_vs, const float* __restrict__ w_vvv,
  bf16* __restrict__ NREC)
{
  __shared__ float nv[16][192];
  __shared__ float vv[16][192];
  const int t=threadIdx.x; const int n0=blockIdx.x*16;
  for(int i=t;i<16*192;i+=256){
    int nn=i/192, c=i-nn*192;
    int v=c/3, k=c-3*v;
    nv[nn][k*64+v]=nf[(size_t)(n0+nn)*320+128+c];
  }
  __syncthreads();
  if(t<192){
    const int k=t>>6, u=t&63;
    float a[16];
    #pragma unroll
    for(int q=0;q<16;q++)a[q]=0.f;
    for(int v=0;v<64;v+=4){
      float w0=Wv_v[v*64+u],w1=Wv_v[(v+1)*64+u],w2=Wv_v[(v+2)*64+u],w3=Wv_v[(v+3)*64+u];
      #pragma unroll
      for(int q=0;q<16;q++){
        const float4 x=*(const float4*)&nv[q][(k<<6)+v];
        a[q]+=x.x*w0+x.y*w1+x.z*w2+x.w*w3;
      }
    }
    #pragma unroll
    for(int q=0;q<16;q++) vv[q][(k<<6)+u]=a[q];
  }
  __syncthreads();
  for(int cch=0;cch<4;cch++){
    int out=t+cch*256;
    if(out>=960) break;
    const float* W; int k,j,ncol,off;
    if(out<384){ k=out>>7; j=out&127; W=w_vv_s; ncol=128; off=256+(k<<7)+j; }
    else if(out<576){ int o=out-384; k=o>>6; j=o&63; W=w_vvg; ncol=64; off=640+(k<<6)+j; }
    else if(out<768){ int o=out-576; k=o>>6; j=o&63; W=w_vs;  ncol=64; off=832+(k<<6)+j; }
    else            { int o=out-768; k=o>>6; j=o&63; W=w_vvv; ncol=64; off=1024+(k<<6)+j; }
    float a[16];
    #pragma unroll
    for(int q=0;q<16;q++)a[q]=0.f;
    for(int v=0;v<64;v+=4){
      float w0=W[v*ncol+j],w1=W[(v+1)*ncol+j],w2=W[(v+2)*ncol+j],w3=W[(v+3)*ncol+j];
      #pragma unroll
      for(int q=0;q<16;q++){
        const float4 x=*(const float4*)&vv[q][(k<<6)+v];
        a[q]+=x.x*w0+x.y*w1+x.z*w2+x.w*w3;
      }
    }
    #pragma unroll
    for(int q=0;q<16;q++) NREC[(size_t)(n0+q)*1216+off]=f2b(a[q]);
  }
}

// ---------------------------------------------------------------------------
// Sort-by-dst (counting sort): histogram -> scan -> scatter
// ---------------------------------------------------------------------------
__global__ __launch_bounds__(256) void k_hist(const int* __restrict__ eidx, int* __restrict__ counts){
  int e=blockIdx.x*256+threadIdx.x;
  if(e<NEDGE) atomicAdd(&counts[eidx[NEDGE+e]],1);
}

__global__ __launch_bounds__(1024) void k_scan(const int* __restrict__ counts, int* __restrict__ off, int* __restrict__ cursor){
  __shared__ int wsum[16];
  __shared__ int woff[17];
  __shared__ int carry_s;
  const int t=threadIdx.x, ln=t&63, wid=t>>6;
  if(t==0) carry_s=0;
  __syncthreads();
  for(int base=0;base<NNODE;base+=1024){
    int idx=base+t;
    int v=(idx<NNODE)?counts[idx]:0;
    int incl=v;
    #pragma unroll
    for(int o=1;o<64;o<<=1){ int x=__shfl_up(incl,o,64); if(ln>=o) incl+=x; }
    if(ln==63) wsum[wid]=incl;
    __syncthreads();
    if(t<16){
      int s=wsum[t];
      #pragma unroll
      for(int o=1;o<16;o<<=1){ int x=__shfl_up(s,o,64); if(t>=o) s+=x; }
      woff[t+1]=s;
      if(t==0) woff[0]=0;
    }
    __syncthreads();
    int excl=carry_s+woff[wid]+(incl-v);
    if(idx<NNODE){ off[idx]=excl; cursor[idx]=excl; }
    __syncthreads();
    if(t==0) carry_s+=woff[16];
    __syncthreads();
  }
  if(t==0) off[NNODE]=NEDGE;
}

__global__ __launch_bounds__(256) void k_scatter(const int* __restrict__ eidx, int* __restrict__ cursor, int* __restrict__ eord){
  int e=blockIdx.x*256+threadIdx.x;
  if(e<NEDGE){
    int d=eidx[NEDGE+e];
    int pos=atomicAdd(&cursor[d],1);
    eord[pos]=e;
  }
}

// ---------------------------------------------------------------------------
// K3: ef = edge_attr@We + be ; raw scores -> SC. 16 edges/block.
// ---------------------------------------------------------------------------
__global__ __launch_bounds__(256) void k3_scores(
  const float* __restrict__ eattr, const int* __restrict__ eidx,
  const float* __restrict__ We, const float* __restrict__ be,
  const bf16* __restrict__ Q, const bf16* __restrict__ K,
  float* __restrict__ SC)
{
  __shared__ float ea[16][64];
  __shared__ int ssrc[16], sdst[16];
  const int t=threadIdx.x; const int e0=blockIdx.x*16;
  for(int i=t;i<16*64;i+=256){ int nn=i>>6,c=i&63; ea[nn][c]=eattr[(size_t)(e0+nn)*64+c]; }
  if(t<16){ ssrc[t]=eidx[e0+t]; sdst[t]=eidx[NEDGE+e0+t]; }
  __syncthreads();
  float a[16];
  #pragma unroll
  for(int q=0;q<16;q++)a[q]=0.f;
  for(int i=0;i<64;i+=4){
    float w0=We[i*256+t],w1=We[(i+1)*256+t],w2=We[(i+2)*256+t],w3=We[(i+3)*256+t];
    #pragma unroll
    for(int q=0;q<16;q++){
      const float4 x=*(const float4*)&ea[q][i];
      a[q]+=x.x*w0+x.y*w1+x.z*w2+x.w*w3;
    }
  }
  const float bev=be[t];
  const int h=t>>4;
  for(int q=0;q<16;q++){
    int s=ssrc[q], d=sdst[q];
    float kv=b2f(K[(size_t)s*256+t]);
    float qv=b2f(Q[(size_t)d*256+t]);
    float v=qv*(kv+a[q]+bev);
    v=gred16(v);
    if((t&15)==0) SC[(size_t)(e0+q)*16+h]=v*0.25f;
  }
}

// ---------------------------------------------------------------------------
// K6: per-dst-node aggregation. One wave per node, 4 nodes/block. No atomics.
// ---------------------------------------------------------------------------
__global__ __launch_bounds__(256) void k6_agg(
  const int* __restrict__ eidx, const float* __restrict__ esh,
  const bf16* __restrict__ NREC, const float* __restrict__ SC,
  const int* __restrict__ OFF, const int* __restrict__ EORD,
  const float* __restrict__ b_ms, const float* __restrict__ b_mg,
  float* __restrict__ AGS, float* __restrict__ AGV)
{
  const int l = threadIdx.x & 63;
  const int n = blockIdx.x*4 + (threadIdx.x>>6);
  const int beg=OFF[n], end=OFF[n+1];
  const float bmsa=b_ms[l], bmsb=b_ms[64+l], bmgv=b_mg[l];

  float mh=-1e30f;
  for(int i=beg;i<end;i++){
    int e=EORD[i];
    if(l<16) mh=fmaxf(mh, SC[(size_t)e*16+l]);
  }
  float dh=0.f;
  for(int i=beg;i<end;i++){
    int e=EORD[i];
    if(l<16) dh+=__expf(SC[(size_t)e*16+l]-mh);
  }
  float rdh = (end>beg && l<16) ? 1.f/dh : 0.f;

  float as0=0.f,as1=0.f,av0acc=0.f,av1acc=0.f,av2acc=0.f;
  for(int i=beg;i<end;i++){
    const int e=EORD[i];
    const int s=eidx[e];
    const float4 sh4=*(const float4*)&esh[(size_t)e*4];
    const float shs=sh4.x, sh0=sh4.y, sh1=sh4.z, sh2=sh4.w;
    float av=(l<16)? __expf(SC[(size_t)e*16+l]-mh)*rdh : 0.f;
    const float att=wred64(av)*(1.f/16.f);

    const bf16* R = NREC + (size_t)s*1216;
    const float s1a=b2f(R[l]),      s1b=b2f(R[64+l]);
    const float s2 =b2f(R[128+l]),  svv=b2f(R[192+l]);
    const float d1a0=b2f(R[256+l]),     d1a1=b2f(R[256+128+l]),  d1a2=b2f(R[256+256+l]);
    const float d1b0=b2f(R[256+64+l]),  d1b1=b2f(R[256+192+l]),  d1b2=b2f(R[256+320+l]);
    const float d20=b2f(R[640+l]),  d21=b2f(R[640+64+l]),  d22=b2f(R[640+128+l]);
    const float w0 =b2f(R[832+l]),  w1 =b2f(R[832+64+l]),  w2 =b2f(R[832+128+l]);
    const float c0 =b2f(R[1024+l]), c1 =b2f(R[1024+64+l]), c2 =b2f(R[1024+128+l]);

    float msa = shs*s1a + d1a0*sh0+d1a1*sh1+d1a2*sh2 + bmsa;
    float msb = shs*s1b + d1b0*sh0+d1b1*sh1+d1b2*sh2 + bmsb;
    float mgv = shs*s2  + d20*sh0 +d21*sh1 +d22*sh2  + bmgv;

    float sum = wred64(msa+msb+mgv);
    float sq  = wred64(msa*msa+msb*msb+mgv*mgv);
    float mean = sum*(1.f/192.f);
    float var  = sq*(1.f/192.f) - mean*mean;
    float rs   = rsqrtf(var + 1e-5f);

    float cr0 = c1*sh2 - c2*sh1;
    float cr1 = c2*sh0 - c0*sh2;
    float cr2 = c0*sh1 - c1*sh0;
    float mv0 = svv*sh0 + shs*w0 + cr0;
    float mv1 = svv*sh1 + shs*w1 + cr1;
    float mv2 = svv*sh2 + shs*w2 + cr2;
    float vsq = wred64(mv0*mv0+mv1*mv1+mv2*mv2);
    float vn  = rsqrtf(vsq*(1.f/64.f) + 1e-5f);

    float sga=(msa-mean)*rs, sgb=(msb-mean)*rs, sgg=(mgv-mean)*rs;
    float wV = vn * sigm(sgg) * att;
    as0 += sga*sigm(sga)*att;
    as1 += sgb*sigm(sgb)*att;
    av0acc += mv0*wV;
    av1acc += mv1*wV;
    av2acc += mv2*wV;
  }
  AGS[(size_t)n*128+l]     =as0;
  AGS[(size_t)n*128+64+l]  =as1;
  AGV[(size_t)n*192+l]     =av0acc;
  AGV[(size_t)n*192+64+l]  =av1acc;
  AGV[(size_t)n*192+128+l] =av2acc;
}

// ---------------------------------------------------------------------------
// Weight prep: pack 6 weight matrices into B-fragment order (bf16).
// tile = 64 lanes x 8 elems; elem j of lane l: k = kt*32+16*(j>>2)+4*(l>>4)+(j&3),
// col = nt*16+(l&15). Tile index within gemm = nt*KT+kt. 1KB per tile.
// ---------------------------------------------------------------------------
#define T_WOS 0
#define T_WOV 32
#define T_W1S 40
#define T_W1V 88
#define T_W2S 96
#define T_W2V 128
#define T_TOT 136

__global__ __launch_bounds__(64) void k_prep(
  const float* __restrict__ Wo_s, const float* __restrict__ Wo_v,
  const float* __restrict__ W1_s, const float* __restrict__ W1_v,
  const float* __restrict__ W2_s, const float* __restrict__ W2_v,
  short* __restrict__ P)
{
  const int T=blockIdx.x, l=threadIdx.x;
  const float* W; int N, KT, lt;
  if(T<T_WOV){ W=Wo_s; N=128; KT=4; lt=T; }
  else if(T<T_W1S){ W=Wo_v; N=64; KT=2; lt=T-T_WOV; }
  else if(T<T_W1V){ W=W1_s; N=192; KT=4; lt=T-T_W1S; }
  else if(T<T_W2S){ W=W1_v; N=64; KT=2; lt=T-T_W1V; }
  else if(T<T_W2V){ W=W2_s; N=128; KT=4; lt=T-T_W2S; }
  else { W=W2_v; N=64; KT=2; lt=T-T_W2V; }
  const int nt=lt/KT, kt=lt-nt*KT;
  const int col=nt*16+(l&15);
  short8v o;
  #pragma unroll
  for(int j=0;j<8;j++){
    int k=kt*32+((j>>2)<<4)+((l>>4)<<2)+(j&3);
    o[j]=f2s(W[(size_t)k*N+col]);
  }
  *(short8v*)(P+((size_t)T<<9)+(l<<3))=o;
}

// ---------------------------------------------------------------------------
// K7 (MFMA): final node update. 16 nodes/block, 4 waves.
// ---------------------------------------------------------------------------
__global__ __launch_bounds__(256) void k7_mfma(
  const float* __restrict__ nf,
  const float* __restrict__ AGS, const float* __restrict__ AGV,
  const short* __restrict__ P,
  const float* __restrict__ bo_s, const float* __restrict__ b1_s, const float* __restrict__ b2_s,
  float* __restrict__ out)
{
  __shared__ float xs[16][132];
  __shared__ float xv[16][196];
  __shared__ float ff[16][196];
  __shared__ short asA[4*512];
  __shared__ short avA[6*512];
  __shared__ float smean[16], srs[16], svn[16];
  const int t=threadIdx.x, l=t&63, w=t>>6;
  const int n0=blockIdx.x*16;

  // ---- P0: residual init + stage agg_s/agg_V into frag-order LDS
  for(int i=t;i<2048;i+=256){ int r=i>>7,c=i&127; xs[r][c]=nf[(size_t)(n0+r)*320+c]; }
  for(int i=t;i<3072;i+=256){ int r=i/192,cc=i-r*192; int k=cc>>6,u=cc&63; xv[r][cc]=nf[(size_t)(n0+r)*320+128+u*3+k]; }
  for(int i=t;i<512;i+=256){
    int r=i>>5, c=(i&31)<<2;
    const float4 v=*(const float4*)&AGS[(size_t)(n0+r)*128+c];
    int kt=c>>5,k32=c&31,half=k32>>4,g=(k32&15)>>2;
    int bo=(kt<<10)+((r+(g<<4))<<4)+(half<<3);
    short4 s; s.x=f2s(v.x); s.y=f2s(v.y); s.z=f2s(v.z); s.w=f2s(v.w);
    *(short4*)((char*)asA+bo)=s;
  }
  for(int i=t;i<768;i+=256){
    int r=i/48, c=(i-r*48)<<2;
    const float4 v=*(const float4*)&AGV[(size_t)(n0+r)*192+c];
    int p=c>>6,u=c&63;
    int kt2=u>>5,k32=u&31,half=k32>>4,g=(k32&15)>>2;
    int bo=(((p<<1)+kt2)<<10)+((r+(g<<4))<<4)+(half<<3);
    short4 s; s.x=f2s(v.x); s.y=f2s(v.y); s.z=f2s(v.z); s.w=f2s(v.w);
    *(short4*)((char*)avA+bo)=s;
  }
  __syncthreads();

  // ---- P1: G1 (agg_s @ Wo_s -> xs+=) and G2 (agg_V @ Wo_v planes -> xv+=)
  {
    short8v a[4];
    #pragma unroll
    for(int kt=0;kt<4;kt++) a[kt]=*(const short8v*)((const char*)asA+(kt<<10)+(l<<4));
    #pragma unroll
    for(int ii=0;ii<2;ii++){
      int nt=w+(ii<<2);
      f32x4 acc={0.f,0.f,0.f,0.f};
      #pragma unroll
      for(int kt=0;kt<4;kt++){
        short8v b=*(const short8v*)(P+(((size_t)(T_WOS+nt*4+kt))<<9)+(l<<3));
        acc=__builtin_amdgcn_mfma_f32_16x16x32_bf16(a[kt],b,acc,0,0,0);
      }
      int col=(nt<<4)+(l&15);
      float bv=bo_s[col];
      #pragma unroll
      for(int r=0;r<4;r++){ int row=((l>>4)<<2)+r; xs[row][col]+=acc[r]+bv; }
    }
    #pragma unroll
    for(int ii=0;ii<3;ii++){
      int tid=w*3+ii, p=tid>>2, nt2=tid&3;
      f32x4 acc={0.f,0.f,0.f,0.f};
      #pragma unroll
      for(int kt=0;kt<2;kt++){
        short8v a2=*(const short8v*)((const char*)avA+(((p<<1)+kt)<<10)+(l<<4));
        short8v b=*(const short8v*)(P+(((size_t)(T_WOV+nt2*2+kt))<<9)+(l<<3));
        acc=__builtin_amdgcn_mfma_f32_16x16x32_bf16(a2,b,acc,0,0,0);
      }
      int col=(p<<6)+(nt2<<4)+(l&15);
      #pragma unroll
      for(int r=0;r<4;r++){ int row=((l>>4)<<2)+r; xv[row][col]+=acc[r]; }
    }
  }
  __syncthreads();

  // ---- P2: LN1 stats
  {
    const int nn=t>>4, g=t&15;
    float sum=0,sq=0;
    #pragma unroll
    for(int j=0;j<8;j++){ float x=xs[nn][g+16*j]; sum+=x; sq+=x*x; }
    sum=gred16(sum); sq=gred16(sq);
    float mean=sum*(1.f/128.f);
    float var=sq*(1.f/128.f)-mean*mean;
    float vsq=0;
    #pragma unroll
    for(int j=0;j<12;j++){ float x=xv[nn][g+16*j]; vsq+=x*x; }
    vsq=gred16(vsq);
    if(g==0){ smean[nn]=mean; srs[nn]=rsqrtf(var+1e-5f); svn[nn]=rsqrtf(vsq*(1.f/64.f)+1e-5f); }
  }
  __syncthreads();

  // ---- P3: normalize in place + re-stage normalized xs/xv into frag LDS
  for(int i=t;i<512;i+=256){
    int r=i>>5, c=(i&31)<<2;
    float m=smean[r], rs=srs[r];
    float4 v=*(float4*)&xs[r][c];
    v.x=(v.x-m)*rs; v.y=(v.y-m)*rs; v.z=(v.z-m)*rs; v.w=(v.w-m)*rs;
    *(float4*)&xs[r][c]=v;
    int kt=c>>5,k32=c&31,half=k32>>4,g=(k32&15)>>2;
    int bo=(kt<<10)+((r+(g<<4))<<4)+(half<<3);
    short4 s; s.x=f2s(v.x); s.y=f2s(v.y); s.z=f2s(v.z); s.w=f2s(v.w);
    *(short4*)((char*)asA+bo)=s;
  }
  for(int i=t;i<768;i+=256){
    int r=i/48, c=(i-r*48)<<2;
    float vn=svn[r];
    float4 v=*(float4*)&xv[r][c];
    v.x*=vn; v.y*=vn; v.z*=vn; v.w*=vn;
    *(float4*)&xv[r][c]=v;
    int p=c>>6,u=c&63;
    int kt2=u>>5,k32=u&31,half=k32>>4,g=(k32&15)>>2;
    int bo=(((p<<1)+kt2)<<10)+((r+(g<<4))<<4)+(half<<3);
    short4 s; s.x=f2s(v.x); s.y=f2s(v.y); s.z=f2s(v.z); s.w=f2s(v.w);
    *(short4*)((char*)avA+bo)=s;
  }
  __syncthreads();

  // ---- P4: G3 (x_s @ W1_s -> ff)
  {
    short8v a[4];
    #pragma unroll
    for(int kt=0;kt<4;kt++) a[kt]=*(const short8v*)((const char*)asA+(kt<<10)+(l<<4));
    #pragma unroll
    for(int ii=0;ii<3;ii++){
      int nt=w+(ii<<2);
      f32x4 acc={0.f,0.f,0.f,0.f};
      #pragma unroll
      for(int kt=0;kt<4;kt++){
        short8v b=*(const short8v*)(P+(((size_t)(T_W1S+nt*4+kt))<<9)+(l<<3));
        acc=__builtin_amdgcn_mfma_f32_16x16x32_bf16(a[kt],b,acc,0,0,0);
      }
      int col=(nt<<4)+(l&15);
      float bv=b1_s[col];
      #pragma unroll
      for(int r=0;r<4;r++){ int row=((l>>4)<<2)+r; ff[row][col]=acc[r]+bv; }
    }
  }
  __syncthreads();

  // ---- P5: G4 compute (x_V @ W1_v, hold acc) + silu(f[:,:128]) -> asA
  f32x4 g4acc[3];
  {
    #pragma unroll
    for(int ii=0;ii<3;ii++){
      int tid=w*3+ii, p=tid>>2, nt2=tid&3;
      f32x4 acc={0.f,0.f,0.f,0.f};
      #pragma unroll
      for(int kt=0;kt<2;kt++){
        short8v a2=*(const short8v*)((const char*)avA+(((p<<1)+kt)<<10)+(l<<4));
        short8v b=*(const short8v*)(P+(((size_t)(T_W1V+nt2*2+kt))<<9)+(l<<3));
        acc=__builtin_amdgcn_mfma_f32_16x16x32_bf16(a2,b,acc,0,0,0);
      }
      g4acc[ii]=acc;
    }
    for(int i=t;i<512;i+=256){
      int r=i>>5, c=(i&31)<<2;
      float4 v=*(float4*)&ff[r][c];
      v.x=v.x*sigm(v.x); v.y=v.y*sigm(v.y); v.z=v.z*sigm(v.z); v.w=v.w*sigm(v.w);
      int kt=c>>5,k32=c&31,half=k32>>4,g=(k32&15)>>2;
      int bo=(kt<<10)+((r+(g<<4))<<4)+(half<<3);
      short4 s; s.x=f2s(v.x); s.y=f2s(v.y); s.z=f2s(v.z); s.w=f2s(v.w);
      *(short4*)((char*)asA+bo)=s;
    }
  }
  __syncthreads();

  // ---- P6: gv = g4acc * sigmoid(f[:,128+u]) -> avA (frag order, b16 writes)
  {
    #pragma unroll
    for(int ii=0;ii<3;ii++){
      int tid=w*3+ii, p=tid>>2, nt2=tid&3;
      int uu=(nt2<<4)+(l&15);
      #pragma unroll
      for(int r=0;r<4;r++){
        int row=((l>>4)<<2)+r;
        float val=g4acc[ii][r]*sigm(ff[row][128+uu]);
        int kt2=uu>>5,k32=uu&31,half=k32>>4,g=(k32&15)>>2,jj=k32&3;
        int bo=(((p<<1)+kt2)<<10)+((row+(g<<4))<<4)+(half<<3)+(jj<<1);
        *(short*)((char*)avA+bo)=f2s(val);
      }
    }
  }
  __syncthreads();

  // ---- P7: G5 (silu(f) @ W2_s -> xs+=) and G6 (gv @ W2_v -> xv+=)
  {
    short8v a[4];
    #pragma unroll
    for(int kt=0;kt<4;kt++) a[kt]=*(const short8v*)((const char*)asA+(kt<<10)+(l<<4));
    #pragma unroll
    for(int ii=0;ii<2;ii++){
      int nt=w+(ii<<2);
      f32x4 acc={0.f,0.f,0.f,0.f};
      #pragma unroll
      for(int kt=0;kt<4;kt++){
        short8v b=*(const short8v*)(P+(((size_t)(T_W2S+nt*4+kt))<<9)+(l<<3));
        acc=__builtin_amdgcn_mfma_f32_16x16x32_bf16(a[kt],b,acc,0,0,0);
      }
      int col=(nt<<4)+(l&15);
      float bv=b2_s[col];
      #pragma unroll
      for(int r=0;r<4;r++){ int row=((l>>4)<<2)+r; xs[row][col]+=acc[r]+bv; }
    }
    #pragma unroll
    for(int ii=0;ii<3;ii++){
      int tid=w*3+ii, p=tid>>2, nt2=tid&3;
      f32x4 acc={0.f,0.f,0.f,0.f};
      #pragma unroll
      for(int kt=0;kt<2;kt++){
        short8v a2=*(const short8v*)((const char*)avA+(((p<<1)+kt)<<10)+(l<<4));
        short8v b=*(const short8v*)(P+(((size_t)(T_W2V+nt2*2+kt))<<9)+(l<<3));
        acc=__builtin_amdgcn_mfma_f32_16x16x32_bf16(a2,b,acc,0,0,0);
      }
      int col=(p<<6)+(nt2<<4)+(l&15);
      #pragma unroll
      for(int r=0;r<4;r++){ int row=((l>>4)<<2)+r; xv[row][col]+=acc[r]; }
    }
  }
  __syncthreads();

  // ---- P8: LN2 stats
  {
    const int nn=t>>4, g=t&15;
    float sum=0,sq=0;
    #pragma unroll
    for(int j=0;j<8;j++){ float x=xs[nn][g+16*j]; sum+=x; sq+=x*x; }
    sum=gred16(sum); sq=gred16(sq);
    float mean=sum*(1.f/128.f);
    float var=sq*(1.f/128.f)-mean*mean;
    float vsq=0;
    #pragma unroll
    for(int j=0;j<12;j++){ float x=xv[nn][g+16*j]; vsq+=x*x; }
    vsq=gred16(vsq);
    if(g==0){ smean[nn]=mean; srs[nn]=rsqrtf(var+1e-5f); svn[nn]=rsqrtf(vsq*(1.f/64.f)+1e-5f); }
  }
  __syncthreads();

  // ---- P9: store
  for(int i=t;i<16*320;i+=256){
    int nn=i/320, c=i-nn*320;
    float v;
    if(c<128) v=(xs[nn][c]-smean[nn])*srs[nn];
    else { int j=c-128; int u=j/3, k=j-u*3; v=xv[nn][(k<<6)+u]*svn[nn]; }
    out[(size_t)(n0+nn)*320+c]=v;
  }
}

// ---------------------------------------------------------------------------
extern "C" void kernel_launch(void* const* d_in, const int* in_sizes, int n_in,
                              void* d_out, int out_size, void* d_ws, size_t ws_size,
                              hipStream_t stream)
{
  (void)in_sizes; (void)n_in; (void)out_size; (void)ws_size;
  const float* nf    =(const float*)d_in[0];
  const float* eattr =(const float*)d_in[1];
  const float* esh   =(const float*)d_in[2];
  const float* Wq    =(const float*)d_in[3];  const float* bq  =(const float*)d_in[4];
  const float* Wk    =(const float*)d_in[5];  const float* bk  =(const float*)d_in[6];
  const float* We    =(const float*)d_in[7];  const float* be  =(const float*)d_in[8];
  const float* Wv_s  =(const float*)d_in[9];  const float* bv_s=(const float*)d_in[10];
  const float* Wv_v  =(const float*)d_in[11];
  const float* w_ss  =(const float*)d_in[12]; const float* w_vv_s=(const float*)d_in[13];
  const float* w_ssg =(const float*)d_in[14]; const float* w_vvg =(const float*)d_in[15];
  const float* b_ms  =(const float*)d_in[16]; const float* b_mg  =(const float*)d_in[17];
  const float* w_sv  =(const float*)d_in[18]; const float* w_vs  =(const float*)d_in[19];
  const float* w_vvv =(const float*)d_in[20];
  const float* Wo_s  =(const float*)d_in[21]; const float* bo_s  =(const float*)d_in[22];
  const float* Wo_v  =(const float*)d_in[23];
  const float* W1_s  =(const float*)d_in[24]; const float* b1_s  =(const float*)d_in[25];
  const float* W1_v  =(const float*)d_in[26];
  const float* W2_s  =(const float*)d_in[27]; const float* b2_s  =(const float*)d_in[28];
  const float* W2_v  =(const float*)d_in[29];
  const int*   eidx  =(const int*)d_in[30];
  float* out=(float*)d_out;

  char* w=(char*)d_ws;
  bf16* Q    =(bf16*)w;  w+=(size_t)NNODE*256*2;
  bf16* Kb   =(bf16*)w;  w+=(size_t)NNODE*256*2;
  bf16* NREC =(bf16*)w;  w+=(size_t)NNODE*1216*2;
  float* SC  =(float*)w; w+=(size_t)NEDGE*16*4;
  float* AGS =(float*)w; w+=(size_t)NNODE*128*4;
  float* AGV =(float*)w; w+=(size_t)NNODE*192*4;
  short* P   =(short*)w; w+=(size_t)T_TOT*512*2;
  int* COUNTS=(int*)w;   w+=(size_t)NNODE*4;
  int* OFFb  =(int*)w;   w+=(size_t)(NNODE+1)*4;
  int* CURSOR=(int*)w;   w+=(size_t)NNODE*4;
  int* EORDb =(int*)w;   w+=(size_t)NEDGE*4;

  hipMemsetAsync(COUNTS,0,(size_t)NNODE*4,stream);

  k_prep        <<<T_TOT,64,0,stream>>>(Wo_s,Wo_v,W1_s,W1_v,W2_s,W2_v,P);
  k_hist        <<<(NEDGE+255)/256,256,0,stream>>>(eidx,COUNTS);
  k_scan        <<<1,1024,0,stream>>>(COUNTS,OFFb,CURSOR);
  k_scatter     <<<(NEDGE+255)/256,256,0,stream>>>(eidx,CURSOR,EORDb);
  k1_node_scalar<<<NNODE/16,256,0,stream>>>(nf,Wq,bq,Wk,bk,Wv_s,bv_s,w_ss,w_ssg,w_sv,Q,Kb,NREC);
  k2_node_vec   <<<NNODE/16,256,0,stream>>>(nf,Wv_v,w_vv_s,w_vvg,w_vs,w_vvv,NREC);
  k3_scores     <<<NEDGE/16,256,0,stream>>>(eattr,eidx,We,be,Q,Kb,SC);
  k6_agg        <<<NNODE/4,256,0,stream>>>(eidx,esh,NREC,SC,OFFb,EORDb,b_ms,b_mg,AGS,AGV);
  k7_mfma       <<<NNODE/16,256,0,stream>>>(nf,AGS,AGV,P,bo_s,b1_s,b2_s,out);
}

// Round 5
// 887.506 us; speedup vs baseline: 1.5513x; 1.2392x over previous
//
#include <hip/hip_runtime.h>
#include <hip/hip_bf16.h>

#define NNODE 50000
#define NEDGE 250000

typedef __hip_bfloat16 bf16;
typedef __attribute__((ext_vector_type(8))) short short8v;
typedef __attribute__((ext_vector_type(4))) float f32x4;

__device__ __forceinline__ float b2f(bf16 x){ return __bfloat162float(x); }
__device__ __forceinline__ bf16  f2b(float x){ return __float2bfloat16(x); }
__device__ __forceinline__ short f2s(float x){ bf16 h=f2b(x); short s; __builtin_memcpy(&s,&h,2); return s; }
__device__ __forceinline__ float s2f(short s){ bf16 h; __builtin_memcpy(&h,&s,2); return b2f(h); }
__device__ __forceinline__ float sigm(float x){ return 1.0f/(1.0f+__expf(-x)); }
__device__ __forceinline__ float wred64(float v){
  #pragma unroll
  for(int o=32;o>0;o>>=1) v+=__shfl_xor(v,o,64);
  return v;
}
__device__ __forceinline__ float gred16(float v){
  v+=__shfl_xor(v,1,64); v+=__shfl_xor(v,2,64); v+=__shfl_xor(v,4,64); v+=__shfl_xor(v,8,64);
  return v;
}

// ---------------------------------------------------------------------------
// K1: per-node scalar path: Q,K (bf16) and NREC[0..256) = {S1(128), S2(64), sv(64)}
// ---------------------------------------------------------------------------
__global__ __launch_bounds__(256) void k1_node_scalar(
  const float* __restrict__ nf,
  const float* __restrict__ Wq, const float* __restrict__ bq,
  const float* __restrict__ Wk, const float* __restrict__ bk,
  const float* __restrict__ Wvs_w, const float* __restrict__ bvs,
  const float* __restrict__ w_ss, const float* __restrict__ w_ssg, const float* __restrict__ w_sv,
  bf16* __restrict__ Q, bf16* __restrict__ K, bf16* __restrict__ NREC)
{
  __shared__ float ns[16][128];
  __shared__ float vs[16][128];
  const int t = threadIdx.x;
  const int n0 = blockIdx.x * 16;
  for(int i=t;i<16*128;i+=256){ int nn=i>>7, c=i&127; ns[nn][c]=nf[(size_t)(n0+nn)*320+c]; }
  __syncthreads();
  {
    float aq[16], ak[16];
    #pragma unroll
    for(int q=0;q<16;q++){aq[q]=0.f;ak[q]=0.f;}
    for(int i=0;i<128;i+=4){
      float wq0=Wq[i*256+t],wq1=Wq[(i+1)*256+t],wq2=Wq[(i+2)*256+t],wq3=Wq[(i+3)*256+t];
      float wk0=Wk[i*256+t],wk1=Wk[(i+1)*256+t],wk2=Wk[(i+2)*256+t],wk3=Wk[(i+3)*256+t];
      #pragma unroll
      for(int q=0;q<16;q++){
        const float4 x=*(const float4*)&ns[q][i];
        aq[q]+=x.x*wq0+x.y*wq1+x.z*wq2+x.w*wq3;
        ak[q]+=x.x*wk0+x.y*wk1+x.z*wk2+x.w*wk3;
      }
    }
    float bqv=bq[t], bkv=bk[t];
    #pragma unroll
    for(int q=0;q<16;q++){
      Q[(size_t)(n0+q)*256+t]=f2b(aq[q]+bqv);
      K[(size_t)(n0+q)*256+t]=f2b(ak[q]+bkv);
    }
  }
  {
    const int c=t&127, hf=t>>7;
    float a[8];
    #pragma unroll
    for(int q=0;q<8;q++)a[q]=0.f;
    for(int i=0;i<128;i+=4){
      float w0=Wvs_w[i*128+c],w1=Wvs_w[(i+1)*128+c],w2=Wvs_w[(i+2)*128+c],w3=Wvs_w[(i+3)*128+c];
      #pragma unroll
      for(int q=0;q<8;q++){
        const float4 x=*(const float4*)&ns[hf*8+q][i];
        a[q]+=x.x*w0+x.y*w1+x.z*w2+x.w*w3;
      }
    }
    float bv=bvs[c];
    #pragma unroll
    for(int q=0;q<8;q++) vs[hf*8+q][c]=a[q]+bv;
  }
  __syncthreads();
  {
    const float* W; int col, ncol;
    if(t<128){ W=w_ss;  col=t;     ncol=128; }
    else if(t<192){ W=w_ssg; col=t-128; ncol=64; }
    else { W=w_sv;  col=t-192; ncol=64; }
    float a[16];
    #pragma unroll
    for(int q=0;q<16;q++)a[q]=0.f;
    for(int i=0;i<128;i+=4){
      float w0=W[i*ncol+col],w1=W[(i+1)*ncol+col],w2=W[(i+2)*ncol+col],w3=W[(i+3)*ncol+col];
      #pragma unroll
      for(int q=0;q<16;q++){
        const float4 x=*(const float4*)&vs[q][i];
        a[q]+=x.x*w0+x.y*w1+x.z*w2+x.w*w3;
      }
    }
    #pragma unroll
    for(int q=0;q<16;q++) NREC[(size_t)(n0+q)*1216+t]=f2b(a[q]);
  }
}

// ---------------------------------------------------------------------------
// K2: per-node vector path: NREC[256..1216) = {D1(3x128), D2(3x64), Wvs(3x64), Cn(3x64)}
// ---------------------------------------------------------------------------
__global__ __launch_bounds__(256) void k2_node_vec(
  const float* __restrict__ nf,
  const float* __restrict__ Wv_v, const float* __restrict__ w_vv_s,
  const float* __restrict__ w_vvg, const float* __restrict__ w_vs, const float* __restrict__ w_vvv,
  bf16* __restrict__ NREC)
{
  __shared__ float nv[16][192];
  __shared__ float vv[16][192];
  const int t=threadIdx.x; const int n0=blockIdx.x*16;
  for(int i=t;i<16*192;i+=256){
    int nn=i/192, c=i-nn*192;
    int v=c/3, k=c-3*v;
    nv[nn][k*64+v]=nf[(size_t)(n0+nn)*320+128+c];
  }
  __syncthreads();
  if(t<192){
    const int k=t>>6, u=t&63;
    float a[16];
    #pragma unroll
    for(int q=0;q<16;q++)a[q]=0.f;
    for(int v=0;v<64;v+=4){
      float w0=Wv_v[v*64+u],w1=Wv_v[(v+1)*64+u],w2=Wv_v[(v+2)*64+u],w3=Wv_v[(v+3)*64+u];
      #pragma unroll
      for(int q=0;q<16;q++){
        const float4 x=*(const float4*)&nv[q][(k<<6)+v];
        a[q]+=x.x*w0+x.y*w1+x.z*w2+x.w*w3;
      }
    }
    #pragma unroll
    for(int q=0;q<16;q++) vv[q][(k<<6)+u]=a[q];
  }
  __syncthreads();
  for(int cch=0;cch<4;cch++){
    int out=t+cch*256;
    if(out>=960) break;
    const float* W; int k,j,ncol,off;
    if(out<384){ k=out>>7; j=out&127; W=w_vv_s; ncol=128; off=256+(k<<7)+j; }
    else if(out<576){ int o=out-384; k=o>>6; j=o&63; W=w_vvg; ncol=64; off=640+(k<<6)+j; }
    else if(out<768){ int o=out-576; k=o>>6; j=o&63; W=w_vs;  ncol=64; off=832+(k<<6)+j; }
    else            { int o=out-768; k=o>>6; j=o&63; W=w_vvv; ncol=64; off=1024+(k<<6)+j; }
    float a[16];
    #pragma unroll
    for(int q=0;q<16;q++)a[q]=0.f;
    for(int v=0;v<64;v+=4){
      float w0=W[v*ncol+j],w1=W[(v+1)*ncol+j],w2=W[(v+2)*ncol+j],w3=W[(v+3)*ncol+j];
      #pragma unroll
      for(int q=0;q<16;q++){
        const float4 x=*(const float4*)&vv[q][(k<<6)+v];
        a[q]+=x.x*w0+x.y*w1+x.z*w2+x.w*w3;
      }
    }
    #pragma unroll
    for(int q=0;q<16;q++) NREC[(size_t)(n0+q)*1216+off]=f2b(a[q]);
  }
}

// ---------------------------------------------------------------------------
// Sort-by-dst (counting sort): histogram -> scan -> scatter
// ---------------------------------------------------------------------------
__global__ __launch_bounds__(256) void k_hist(const int* __restrict__ eidx, int* __restrict__ counts){
  int e=blockIdx.x*256+threadIdx.x;
  if(e<NEDGE) atomicAdd(&counts[eidx[NEDGE+e]],1);
}

__global__ __launch_bounds__(1024) void k_scan(const int* __restrict__ counts, int* __restrict__ off, int* __restrict__ cursor){
  __shared__ int wsum[16];
  __shared__ int woff[17];
  __shared__ int carry_s;
  const int t=threadIdx.x, ln=t&63, wid=t>>6;
  if(t==0) carry_s=0;
  __syncthreads();
  for(int base=0;base<NNODE;base+=1024){
    int idx=base+t;
    int v=(idx<NNODE)?counts[idx]:0;
    int incl=v;
    #pragma unroll
    for(int o=1;o<64;o<<=1){ int x=__shfl_up(incl,o,64); if(ln>=o) incl+=x; }
    if(ln==63) wsum[wid]=incl;
    __syncthreads();
    if(t<16){
      int s=wsum[t];
      #pragma unroll
      for(int o=1;o<16;o<<=1){ int x=__shfl_up(s,o,64); if(t>=o) s+=x; }
      woff[t+1]=s;
      if(t==0) woff[0]=0;
    }
    __syncthreads();
    int excl=carry_s+woff[wid]+(incl-v);
    if(idx<NNODE){ off[idx]=excl; cursor[idx]=excl; }
    __syncthreads();
    if(t==0) carry_s+=woff[16];
    __syncthreads();
  }
  if(t==0) off[NNODE]=NEDGE;
}

__global__ __launch_bounds__(256) void k_scatter(const int* __restrict__ eidx, int* __restrict__ cursor, int* __restrict__ eord){
  int e=blockIdx.x*256+threadIdx.x;
  if(e<NEDGE){
    int d=eidx[NEDGE+e];
    int pos=atomicAdd(&cursor[d],1);
    eord[pos]=e;
  }
}

// ---------------------------------------------------------------------------
// Weight prep: pack weight matrices into B-fragment order (bf16).
// ---------------------------------------------------------------------------
#define T_WOS 0
#define T_WOV 32
#define T_W1S 40
#define T_W1V 88
#define T_W2S 96
#define T_W2V 128
#define T_WE  136
#define T_TOT 168

__global__ __launch_bounds__(64) void k_prep(
  const float* __restrict__ Wo_s, const float* __restrict__ Wo_v,
  const float* __restrict__ W1_s, const float* __restrict__ W1_v,
  const float* __restrict__ W2_s, const float* __restrict__ W2_v,
  const float* __restrict__ WeM,
  short* __restrict__ P)
{
  const int T=blockIdx.x, l=threadIdx.x;
  const float* W; int N, KT, lt;
  if(T<T_WOV){ W=Wo_s; N=128; KT=4; lt=T; }
  else if(T<T_W1S){ W=Wo_v; N=64; KT=2; lt=T-T_WOV; }
  else if(T<T_W1V){ W=W1_s; N=192; KT=4; lt=T-T_W1S; }
  else if(T<T_W2S){ W=W1_v; N=64; KT=2; lt=T-T_W1V; }
  else if(T<T_W2V){ W=W2_s; N=128; KT=4; lt=T-T_W2S; }
  else if(T<T_WE){ W=W2_v; N=64; KT=2; lt=T-T_W2V; }
  else { W=WeM; N=256; KT=2; lt=T-T_WE; }
  const int nt=lt/KT, kt=lt-nt*KT;
  const int col=nt*16+(l&15);
  short8v o;
  #pragma unroll
  for(int j=0;j<8;j++){
    int k=kt*32+((j>>2)<<4)+((l>>4)<<2)+(j&3);
    o[j]=f2s(W[(size_t)k*N+col]);
  }
  *(short8v*)(P+((size_t)T<<9)+(l<<3))=o;
}

// ---------------------------------------------------------------------------
// K3 (MFMA): ef = edge_attr@We + be via matrix cores; scores -> SC.
// 16 edges/block, 4 waves.
// ---------------------------------------------------------------------------
__global__ __launch_bounds__(256) void k3_mfma(
  const float* __restrict__ eattr, const int* __restrict__ eidx,
  const short* __restrict__ P, const float* __restrict__ be,
  const bf16* __restrict__ Q, const bf16* __restrict__ K,
  float* __restrict__ SC)
{
  __shared__ __align__(16) short aeF[2*512];
  __shared__ __align__(16) float ef[16][260];
  __shared__ int ssrc[16], sdst[16];
  const int t=threadIdx.x, l=t&63, w=t>>6;
  const int e0=blockIdx.x*16;
  if(t<16){ ssrc[t]=eidx[e0+t]; sdst[t]=eidx[NEDGE+e0+t]; }
  {
    int r=t>>4, c4=(t&15)<<2;
    const float4 v=*(const float4*)&eattr[(size_t)(e0+r)*64+c4];
    int kt=c4>>5,k32=c4&31,half=k32>>4,g=(k32&15)>>2;
    int bo=(kt<<10)+((r+(g<<4))<<4)+(half<<3);
    short4 s; s.x=f2s(v.x); s.y=f2s(v.y); s.z=f2s(v.z); s.w=f2s(v.w);
    *(short4*)((char*)aeF+bo)=s;
  }
  __syncthreads();
  {
    short8v a0=*(const short8v*)((const char*)aeF+(l<<4));
    short8v a1=*(const short8v*)((const char*)aeF+1024+(l<<4));
    #pragma unroll
    for(int ii=0;ii<4;ii++){
      int nt=w+(ii<<2);
      f32x4 acc={0.f,0.f,0.f,0.f};
      short8v b0=*(const short8v*)(P+(((size_t)(T_WE+nt*2+0))<<9)+(l<<3));
      short8v b1=*(const short8v*)(P+(((size_t)(T_WE+nt*2+1))<<9)+(l<<3));
      acc=__builtin_amdgcn_mfma_f32_16x16x32_bf16(a0,b0,acc,0,0,0);
      acc=__builtin_amdgcn_mfma_f32_16x16x32_bf16(a1,b1,acc,0,0,0);
      int col=(nt<<4)+(l&15);
      float bv=be[col];
      #pragma unroll
      for(int r=0;r<4;r++){ int row=((l>>4)<<2)+r; ef[row][col]=acc[r]+bv; }
    }
  }
  __syncthreads();
  {
    const int h=l&15, qt=l>>4;
    const int ch=h*16+(qt<<2);
    #pragma unroll
    for(int j=0;j<4;j++){
      int el=w*4+j;
      int s=ssrc[el], d=sdst[el];
      short4 qs=*(const short4*)((const short*)Q+(size_t)d*256+ch);
      short4 ks=*(const short4*)((const short*)K+(size_t)s*256+ch);
      const float4 e4=*(const float4*)&ef[el][ch];
      float p = s2f(qs.x)*(s2f(ks.x)+e4.x)
              + s2f(qs.y)*(s2f(ks.y)+e4.y)
              + s2f(qs.z)*(s2f(ks.z)+e4.z)
              + s2f(qs.w)*(s2f(ks.w)+e4.w);
      p += __shfl_xor(p,16,64);
      p += __shfl_xor(p,32,64);
      if(qt==0) SC[(size_t)(e0+el)*16+h]=p*0.25f;
    }
  }
}

// ---------------------------------------------------------------------------
// K6: per-dst-node aggregation. One wave per node, 4 nodes/block. No atomics.
// ---------------------------------------------------------------------------
__global__ __launch_bounds__(256) void k6_agg(
  const int* __restrict__ eidx, const float* __restrict__ esh,
  const bf16* __restrict__ NREC, const float* __restrict__ SC,
  const int* __restrict__ OFF, const int* __restrict__ EORD,
  const float* __restrict__ b_ms, const float* __restrict__ b_mg,
  float* __restrict__ AGS, float* __restrict__ AGV)
{
  const int l = threadIdx.x & 63;
  const int n = blockIdx.x*4 + (threadIdx.x>>6);
  const int beg=OFF[n], end=OFF[n+1];
  const float bmsa=b_ms[l], bmsb=b_ms[64+l], bmgv=b_mg[l];

  float mh=-1e30f;
  for(int i=beg;i<end;i++){
    int e=EORD[i];
    if(l<16) mh=fmaxf(mh, SC[(size_t)e*16+l]);
  }
  float dh=0.f;
  for(int i=beg;i<end;i++){
    int e=EORD[i];
    if(l<16) dh+=__expf(SC[(size_t)e*16+l]-mh);
  }
  float rdh = (end>beg && l<16) ? 1.f/dh : 0.f;

  float as0=0.f,as1=0.f,av0acc=0.f,av1acc=0.f,av2acc=0.f;
  for(int i=beg;i<end;i++){
    const int e=EORD[i];
    const int s=eidx[e];
    const float4 sh4=*(const float4*)&esh[(size_t)e*4];
    const float shs=sh4.x, sh0=sh4.y, sh1=sh4.z, sh2=sh4.w;
    float av=(l<16)? __expf(SC[(size_t)e*16+l]-mh)*rdh : 0.f;
    const float att=wred64(av)*(1.f/16.f);

    const bf16* R = NREC + (size_t)s*1216;
    const float s1a=b2f(R[l]),      s1b=b2f(R[64+l]);
    const float s2 =b2f(R[128+l]),  svv=b2f(R[192+l]);
    const float d1a0=b2f(R[256+l]),     d1a1=b2f(R[256+128+l]),  d1a2=b2f(R[256+256+l]);
    const float d1b0=b2f(R[256+64+l]),  d1b1=b2f(R[256+192+l]),  d1b2=b2f(R[256+320+l]);
    const float d20=b2f(R[640+l]),  d21=b2f(R[640+64+l]),  d22=b2f(R[640+128+l]);
    const float w0 =b2f(R[832+l]),  w1 =b2f(R[832+64+l]),  w2 =b2f(R[832+128+l]);
    const float c0 =b2f(R[1024+l]), c1 =b2f(R[1024+64+l]), c2 =b2f(R[1024+128+l]);

    float msa = shs*s1a + d1a0*sh0+d1a1*sh1+d1a2*sh2 + bmsa;
    float msb = shs*s1b + d1b0*sh0+d1b1*sh1+d1b2*sh2 + bmsb;
    float mgv = shs*s2  + d20*sh0 +d21*sh1 +d22*sh2  + bmgv;

    float sum = wred64(msa+msb+mgv);
    float sq  = wred64(msa*msa+msb*msb+mgv*mgv);
    float mean = sum*(1.f/192.f);
    float var  = sq*(1.f/192.f) - mean*mean;
    float rs   = rsqrtf(var + 1e-5f);

    float cr0 = c1*sh2 - c2*sh1;
    float cr1 = c2*sh0 - c0*sh2;
    float cr2 = c0*sh1 - c1*sh0;
    float mv0 = svv*sh0 + shs*w0 + cr0;
    float mv1 = svv*sh1 + shs*w1 + cr1;
    float mv2 = svv*sh2 + shs*w2 + cr2;
    float vsq = wred64(mv0*mv0+mv1*mv1+mv2*mv2);
    float vn  = rsqrtf(vsq*(1.f/64.f) + 1e-5f);

    float sga=(msa-mean)*rs, sgb=(msb-mean)*rs, sgg=(mgv-mean)*rs;
    float wV = vn * sigm(sgg) * att;
    as0 += sga*sigm(sga)*att;
    as1 += sgb*sigm(sgb)*att;
    av0acc += mv0*wV;
    av1acc += mv1*wV;
    av2acc += mv2*wV;
  }
  AGS[(size_t)n*128+l]     =as0;
  AGS[(size_t)n*128+64+l]  =as1;
  AGV[(size_t)n*192+l]     =av0acc;
  AGV[(size_t)n*192+64+l]  =av1acc;
  AGV[(size_t)n*192+128+l] =av2acc;
}

// ---------------------------------------------------------------------------
// K7 (MFMA): final node update. 16 nodes/block, 4 waves.
// ---------------------------------------------------------------------------
__global__ __launch_bounds__(256) void k7_mfma(
  const float* __restrict__ nf,
  const float* __restrict__ AGS, const float* __restrict__ AGV,
  const short* __restrict__ P,
  const float* __restrict__ bo_s, const float* __restrict__ b1_s, const float* __restrict__ b2_s,
  float* __restrict__ out)
{
  __shared__ float xs[16][132];
  __shared__ float xv[16][196];
  __shared__ float ff[16][196];
  __shared__ short asA[4*512];
  __shared__ short avA[6*512];
  __shared__ float smean[16], srs[16], svn[16];
  const int t=threadIdx.x, l=t&63, w=t>>6;
  const int n0=blockIdx.x*16;

  for(int i=t;i<2048;i+=256){ int r=i>>7,c=i&127; xs[r][c]=nf[(size_t)(n0+r)*320+c]; }
  for(int i=t;i<3072;i+=256){ int r=i/192,cc=i-r*192; int k=cc>>6,u=cc&63; xv[r][cc]=nf[(size_t)(n0+r)*320+128+u*3+k]; }
  for(int i=t;i<512;i+=256){
    int r=i>>5, c=(i&31)<<2;
    const float4 v=*(const float4*)&AGS[(size_t)(n0+r)*128+c];
    int kt=c>>5,k32=c&31,half=k32>>4,g=(k32&15)>>2;
    int bo=(kt<<10)+((r+(g<<4))<<4)+(half<<3);
    short4 s; s.x=f2s(v.x); s.y=f2s(v.y); s.z=f2s(v.z); s.w=f2s(v.w);
    *(short4*)((char*)asA+bo)=s;
  }
  for(int i=t;i<768;i+=256){
    int r=i/48, c=(i-r*48)<<2;
    const float4 v=*(const float4*)&AGV[(size_t)(n0+r)*192+c];
    int p=c>>6,u=c&63;
    int kt2=u>>5,k32=u&31,half=k32>>4,g=(k32&15)>>2;
    int bo=(((p<<1)+kt2)<<10)+((r+(g<<4))<<4)+(half<<3);
    short4 s; s.x=f2s(v.x); s.y=f2s(v.y); s.z=f2s(v.z); s.w=f2s(v.w);
    *(short4*)((char*)avA+bo)=s;
  }
  __syncthreads();

  {
    short8v a[4];
    #pragma unroll
    for(int kt=0;kt<4;kt++) a[kt]=*(const short8v*)((const char*)asA+(kt<<10)+(l<<4));
    #pragma unroll
    for(int ii=0;ii<2;ii++){
      int nt=w+(ii<<2);
      f32x4 acc={0.f,0.f,0.f,0.f};
      #pragma unroll
      for(int kt=0;kt<4;kt++){
        short8v b=*(const short8v*)(P+(((size_t)(T_WOS+nt*4+kt))<<9)+(l<<3));
        acc=__builtin_amdgcn_mfma_f32_16x16x32_bf16(a[kt],b,acc,0,0,0);
      }
      int col=(nt<<4)+(l&15);
      float bv=bo_s[col];
      #pragma unroll
      for(int r=0;r<4;r++){ int row=((l>>4)<<2)+r; xs[row][col]+=acc[r]+bv; }
    }
    #pragma unroll
    for(int ii=0;ii<3;ii++){
      int tid=w*3+ii, p=tid>>2, nt2=tid&3;
      f32x4 acc={0.f,0.f,0.f,0.f};
      #pragma unroll
      for(int kt=0;kt<2;kt++){
        short8v a2=*(const short8v*)((const char*)avA+(((p<<1)+kt)<<10)+(l<<4));
        short8v b=*(const short8v*)(P+(((size_t)(T_WOV+nt2*2+kt))<<9)+(l<<3));
        acc=__builtin_amdgcn_mfma_f32_16x16x32_bf16(a2,b,acc,0,0,0);
      }
      int col=(p<<6)+(nt2<<4)+(l&15);
      #pragma unroll
      for(int r=0;r<4;r++){ int row=((l>>4)<<2)+r; xv[row][col]+=acc[r]; }
    }
  }
  __syncthreads();

  {
    const int nn=t>>4, g=t&15;
    float sum=0,sq=0;
    #pragma unroll
    for(int j=0;j<8;j++){ float x=xs[nn][g+16*j]; sum+=x; sq+=x*x; }
    sum=gred16(sum); sq=gred16(sq);
    float mean=sum*(1.f/128.f);
    float var=sq*(1.f/128.f)-mean*mean;
    float vsq=0;
    #pragma unroll
    for(int j=0;j<12;j++){ float x=xv[nn][g+16*j]; vsq+=x*x; }
    vsq=gred16(vsq);
    if(g==0){ smean[nn]=mean; srs[nn]=rsqrtf(var+1e-5f); svn[nn]=rsqrtf(vsq*(1.f/64.f)+1e-5f); }
  }
  __syncthreads();

  for(int i=t;i<512;i+=256){
    int r=i>>5, c=(i&31)<<2;
    float m=smean[r], rs=srs[r];
    float4 v=*(float4*)&xs[r][c];
    v.x=(v.x-m)*rs; v.y=(v.y-m)*rs; v.z=(v.z-m)*rs; v.w=(v.w-m)*rs;
    *(float4*)&xs[r][c]=v;
    int kt=c>>5,k32=c&31,half=k32>>4,g=(k32&15)>>2;
    int bo=(kt<<10)+((r+(g<<4))<<4)+(half<<3);
    short4 s; s.x=f2s(v.x); s.y=f2s(v.y); s.z=f2s(v.z); s.w=f2s(v.w);
    *(short4*)((char*)asA+bo)=s;
  }
  for(int i=t;i<768;i+=256){
    int r=i/48, c=(i-r*48)<<2;
    float vn=svn[r];
    float4 v=*(float4*)&xv[r][c];
    v.x*=vn; v.y*=vn; v.z*=vn; v.w*=vn;
    *(float4*)&xv[r][c]=v;
    int p=c>>6,u=c&63;
    int kt2=u>>5,k32=u&31,half=k32>>4,g=(k32&15)>>2;
    int bo=(((p<<1)+kt2)<<10)+((r+(g<<4))<<4)+(half<<3);
    short4 s; s.x=f2s(v.x); s.y=f2s(v.y); s.z=f2s(v.z); s.w=f2s(v.w);
    *(short4*)((char*)avA+bo)=s;
  }
  __syncthreads();

  {
    short8v a[4];
    #pragma unroll
    for(int kt=0;kt<4;kt++) a[kt]=*(const short8v*)((const char*)asA+(kt<<10)+(l<<4));
    #pragma unroll
    for(int ii=0;ii<3;ii++){
      int nt=w+(ii<<2);
      f32x4 acc={0.f,0.f,0.f,0.f};
      #pragma unroll
      for(int kt=0;kt<4;kt++){
        short8v b=*(const short8v*)(P+(((size_t)(T_W1S+nt*4+kt))<<9)+(l<<3));
        acc=__builtin_amdgcn_mfma_f32_16x16x32_bf16(a[kt],b,acc,0,0,0);
      }
      int col=(nt<<4)+(l&15);
      float bv=b1_s[col];
      #pragma unroll
      for(int r=0;r<4;r++){ int row=((l>>4)<<2)+r; ff[row][col]=acc[r]+bv; }
    }
  }
  __syncthreads();

  f32x4 g4acc[3];
  {
    #pragma unroll
    for(int ii=0;ii<3;ii++){
      int tid=w*3+ii, p=tid>>2, nt2=tid&3;
      f32x4 acc={0.f,0.f,0.f,0.f};
      #pragma unroll
      for(int kt=0;kt<2;kt++){
        short8v a2=*(const short8v*)((const char*)avA+(((p<<1)+kt)<<10)+(l<<4));
        short8v b=*(const short8v*)(P+(((size_t)(T_W1V+nt2*2+kt))<<9)+(l<<3));
        acc=__builtin_amdgcn_mfma_f32_16x16x32_bf16(a2,b,acc,0,0,0);
      }
      g4acc[ii]=acc;
    }
    for(int i=t;i<512;i+=256){
      int r=i>>5, c=(i&31)<<2;
      float4 v=*(float4*)&ff[r][c];
      v.x=v.x*sigm(v.x); v.y=v.y*sigm(v.y); v.z=v.z*sigm(v.z); v.w=v.w*sigm(v.w);
      int kt=c>>5,k32=c&31,half=k32>>4,g=(k32&15)>>2;
      int bo=(kt<<10)+((r+(g<<4))<<4)+(half<<3);
      short4 s; s.x=f2s(v.x); s.y=f2s(v.y); s.z=f2s(v.z); s.w=f2s(v.w);
      *(short4*)((char*)asA+bo)=s;
    }
  }
  __syncthreads();

  {
    #pragma unroll
    for(int ii=0;ii<3;ii++){
      int tid=w*3+ii, p=tid>>2, nt2=tid&3;
      int uu=(nt2<<4)+(l&15);
      #pragma unroll
      for(int r=0;r<4;r++){
        int row=((l>>4)<<2)+r;
        float val=g4acc[ii][r]*sigm(ff[row][128+uu]);
        int kt2=uu>>5,k32=uu&31,half=k32>>4,g=(k32&15)>>2,jj=k32&3;
        int bo=(((p<<1)+kt2)<<10)+((row+(g<<4))<<4)+(half<<3)+(jj<<1);
        *(short*)((char*)avA+bo)=f2s(val);
      }
    }
  }
  __syncthreads();

  {
    short8v a[4];
    #pragma unroll
    for(int kt=0;kt<4;kt++) a[kt]=*(const short8v*)((const char*)asA+(kt<<10)+(l<<4));
    #pragma unroll
    for(int ii=0;ii<2;ii++){
      int nt=w+(ii<<2);
      f32x4 acc={0.f,0.f,0.f,0.f};
      #pragma unroll
      for(int kt=0;kt<4;kt++){
        short8v b=*(const short8v*)(P+(((size_t)(T_W2S+nt*4+kt))<<9)+(l<<3));
        acc=__builtin_amdgcn_mfma_f32_16x16x32_bf16(a[kt],b,acc,0,0,0);
      }
      int col=(nt<<4)+(l&15);
      float bv=b2_s[col];
      #pragma unroll
      for(int r=0;r<4;r++){ int row=((l>>4)<<2)+r; xs[row][col]+=acc[r]+bv; }
    }
    #pragma unroll
    for(int ii=0;ii<3;ii++){
      int tid=w*3+ii, p=tid>>2, nt2=tid&3;
      f32x4 acc={0.f,0.f,0.f,0.f};
      #pragma unroll
      for(int kt=0;kt<2;kt++){
        short8v a2=*(const short8v*)((const char*)avA+(((p<<1)+kt)<<10)+(l<<4));
        short8v b=*(const short8v*)(P+(((size_t)(T_W2V+nt2*2+kt))<<9)+(l<<3));
        acc=__builtin_amdgcn_mfma_f32_16x16x32_bf16(a2,b,acc,0,0,0);
      }
      int col=(p<<6)+(nt2<<4)+(l&15);
      #pragma unroll
      for(int r=0;r<4;r++){ int row=((l>>4)<<2)+r; xv[row][col]+=acc[r]; }
    }
  }
  __syncthreads();

  {
    const int nn=t>>4, g=t&15;
    float sum=0,sq=0;
    #pragma unroll
    for(int j=0;j<8;j++){ float x=xs[nn][g+16*j]; sum+=x; sq+=x*x; }
    sum=gred16(sum); sq=gred16(sq);
    float mean=sum*(1.f/128.f);
    float var=sq*(1.f/128.f)-mean*mean;
    float vsq=0;
    #pragma unroll
    for(int j=0;j<12;j++){ float x=xv[nn][g+16*j]; vsq+=x*x; }
    vsq=gred16(vsq);
    if(g==0){ smean[nn]=mean; srs[nn]=rsqrtf(var+1e-5f); svn[nn]=rsqrtf(vsq*(1.f/64.f)+1e-5f); }
  }
  __syncthreads();

  for(int i=t;i<16*320;i+=256){
    int nn=i/320, c=i-nn*320;
    float v;
    if(c<128) v=(xs[nn][c]-smean[nn])*srs[nn];
    else { int j=c-128; int u=j/3, k=j-u*3; v=xv[nn][(k<<6)+u]*svn[nn]; }
    out[(size_t)(n0+nn)*320+c]=v;
  }
}

// ---------------------------------------------------------------------------
extern "C" void kernel_launch(void* const* d_in, const int* in_sizes, int n_in,
                              void* d_out, int out_size, void* d_ws, size_t ws_size,
                              hipStream_t stream)
{
  (void)in_sizes; (void)n_in; (void)out_size; (void)ws_size;
  const float* nf    =(const float*)d_in[0];
  const float* eattr =(const float*)d_in[1];
  const float* esh   =(const float*)d_in[2];
  const float* Wq    =(const float*)d_in[3];  const float* bq  =(const float*)d_in[4];
  const float* Wk    =(const float*)d_in[5];  const float* bk  =(const float*)d_in[6];
  const float* We    =(const float*)d_in[7];  const float* be  =(const float*)d_in[8];
  const float* Wv_s  =(const float*)d_in[9];  const float* bv_s=(const float*)d_in[10];
  const float* Wv_v  =(const float*)d_in[11];
  const float* w_ss  =(const float*)d_in[12]; const float* w_vv_s=(const float*)d_in[13];
  const float* w_ssg =(const float*)d_in[14]; const float* w_vvg =(const float*)d_in[15];
  const float* b_ms  =(const float*)d_in[16]; const float* b_mg  =(const float*)d_in[17];
  const float* w_sv  =(const float*)d_in[18]; const float* w_vs  =(const float*)d_in[19];
  const float* w_vvv =(const float*)d_in[20];
  const float* Wo_s  =(const float*)d_in[21]; const float* bo_s  =(const float*)d_in[22];
  const float* Wo_v  =(const float*)d_in[23];
  const float* W1_s  =(const float*)d_in[24]; const float* b1_s  =(const float*)d_in[25];
  const float* W1_v  =(const float*)d_in[26];
  const float* W2_s  =(const float*)d_in[27]; const float* b2_s  =(const float*)d_in[28];
  const float* W2_v  =(const float*)d_in[29];
  const int*   eidx  =(const int*)d_in[30];
  float* out=(float*)d_out;

  char* w=(char*)d_ws;
  bf16* Q    =(bf16*)w;  w+=(size_t)NNODE*256*2;
  bf16* Kb   =(bf16*)w;  w+=(size_t)NNODE*256*2;
  bf16* NREC =(bf16*)w;  w+=(size_t)NNODE*1216*2;
  float* SC  =(float*)w; w+=(size_t)NEDGE*16*4;
  float* AGS =(float*)w; w+=(size_t)NNODE*128*4;
  float* AGV =(float*)w; w+=(size_t)NNODE*192*4;
  short* P   =(short*)w; w+=(size_t)T_TOT*512*2;
  int* COUNTS=(int*)w;   w+=(size_t)NNODE*4;
  int* OFFb  =(int*)w;   w+=(size_t)(NNODE+1)*4;
  int* CURSOR=(int*)w;   w+=(size_t)NNODE*4;
  int* EORDb =(int*)w;   w+=(size_t)NEDGE*4;

  hipMemsetAsync(COUNTS,0,(size_t)NNODE*4,stream);

  k_prep        <<<T_TOT,64,0,stream>>>(Wo_s,Wo_v,W1_s,W1_v,W2_s,W2_v,We,P);
  k_hist        <<<(NEDGE+255)/256,256,0,stream>>>(eidx,COUNTS);
  k_scan        <<<1,1024,0,stream>>>(COUNTS,OFFb,CURSOR);
  k_scatter     <<<(NEDGE+255)/256,256,0,stream>>>(eidx,CURSOR,EORDb);
  k1_node_scalar<<<NNODE/16,256,0,stream>>>(nf,Wq,bq,Wk,bk,Wv_s,bv_s,w_ss,w_ssg,w_sv,Q,Kb,NREC);
  k2_node_vec   <<<NNODE/16,256,0,stream>>>(nf,Wv_v,w_vv_s,w_vvg,w_vs,w_vvv,NREC);
  k3_mfma       <<<NEDGE/16,256,0,stream>>>(eattr,eidx,P,be,Q,Kb,SC);
  k6_agg        <<<NNODE/4,256,0,stream>>>(eidx,esh,NREC,SC,OFFb,EORDb,b_ms,b_mg,AGS,AGV);
  k7_mfma       <<<NNODE/16,256,0,stream>>>(nf,AGS,AGV,P,bo_s,b1_s,b2_s,out);
}

// Round 6
// 523.781 us; speedup vs baseline: 2.6286x; 1.6944x over previous
//
#include <hip/hip_runtime.h>
#include <hip/hip_bf16.h>

#define NNODE 50000
#define NEDGE 250000

typedef __hip_bfloat16 bf16;
typedef __attribute__((ext_vector_type(8))) short short8v;
typedef __attribute__((ext_vector_type(4))) float f32x4;

__device__ __forceinline__ float b2f(bf16 x){ return __bfloat162float(x); }
__device__ __forceinline__ bf16  f2b(float x){ return __float2bfloat16(x); }
__device__ __forceinline__ short f2s(float x){ bf16 h=f2b(x); short s; __builtin_memcpy(&s,&h,2); return s; }
__device__ __forceinline__ float s2f(short s){ bf16 h; __builtin_memcpy(&h,&s,2); return b2f(h); }
__device__ __forceinline__ float sigm(float x){ return 1.0f/(1.0f+__expf(-x)); }
__device__ __forceinline__ float wred64(float v){
  #pragma unroll
  for(int o=32;o>0;o>>=1) v+=__shfl_xor(v,o,64);
  return v;
}
__device__ __forceinline__ float gred16(float v){
  v+=__shfl_xor(v,1,64); v+=__shfl_xor(v,2,64); v+=__shfl_xor(v,4,64); v+=__shfl_xor(v,8,64);
  return v;
}
// byte offset of element (row r, k) inside a multi-kt A-frag region (kt stride 1024B)
__device__ __forceinline__ int fragOff(int r, int k){
  int kt=k>>5, k32=k&31, half=k32>>4, g=(k32&15)>>2, j=k32&3;
  return (kt<<10)+((r+(g<<4))<<4)+(half<<3)+(j<<1);
}

// ---------------------------------------------------------------------------
// Weight-prep tile map (each tile 1KB: 64 lanes x 8 bf16)
// ---------------------------------------------------------------------------
#define T_WOS 0
#define T_WOV 32
#define T_W1S 40
#define T_W1V 88
#define T_W2S 96
#define T_W2V 128
#define T_WE  136
#define T_WQ  168
#define T_WK  232
#define T_WVS 296
#define T_WSS 328
#define T_WSSG 360
#define T_WSV 376
#define T_WVV 392
#define T_WVVS 400
#define T_WVVG 416
#define T_WVS2 424
#define T_WVVV 432
#define T_TOT 440

__global__ __launch_bounds__(64) void k_prep(
  const float* __restrict__ Wo_s, const float* __restrict__ Wo_v,
  const float* __restrict__ W1_s, const float* __restrict__ W1_v,
  const float* __restrict__ W2_s, const float* __restrict__ W2_v,
  const float* __restrict__ WeM,
  const float* __restrict__ Wq, const float* __restrict__ Wk,
  const float* __restrict__ Wv_s,
  const float* __restrict__ w_ss, const float* __restrict__ w_ssg,
  const float* __restrict__ w_sv,
  const float* __restrict__ Wv_v, const float* __restrict__ w_vv_s,
  const float* __restrict__ w_vvg, const float* __restrict__ w_vs,
  const float* __restrict__ w_vvv,
  short* __restrict__ P)
{
  const int T=blockIdx.x, l=threadIdx.x;
  const float* W; int N, KT, lt;
  if(T<T_WOV){ W=Wo_s; N=128; KT=4; lt=T; }
  else if(T<T_W1S){ W=Wo_v; N=64; KT=2; lt=T-T_WOV; }
  else if(T<T_W1V){ W=W1_s; N=192; KT=4; lt=T-T_W1S; }
  else if(T<T_W2S){ W=W1_v; N=64; KT=2; lt=T-T_W1V; }
  else if(T<T_W2V){ W=W2_s; N=128; KT=4; lt=T-T_W2S; }
  else if(T<T_WE){ W=W2_v; N=64; KT=2; lt=T-T_W2V; }
  else if(T<T_WQ){ W=WeM; N=256; KT=2; lt=T-T_WE; }
  else if(T<T_WK){ W=Wq; N=256; KT=4; lt=T-T_WQ; }
  else if(T<T_WVS){ W=Wk; N=256; KT=4; lt=T-T_WK; }
  else if(T<T_WSS){ W=Wv_s; N=128; KT=4; lt=T-T_WVS; }
  else if(T<T_WSSG){ W=w_ss; N=128; KT=4; lt=T-T_WSS; }
  else if(T<T_WSV){ W=w_ssg; N=64; KT=4; lt=T-T_WSSG; }
  else if(T<T_WVV){ W=w_sv; N=64; KT=4; lt=T-T_WSV; }
  else if(T<T_WVVS){ W=Wv_v; N=64; KT=2; lt=T-T_WVV; }
  else if(T<T_WVVG){ W=w_vv_s; N=128; KT=2; lt=T-T_WVVS; }
  else if(T<T_WVS2){ W=w_vvg; N=64; KT=2; lt=T-T_WVVG; }
  else if(T<T_WVVV){ W=w_vs; N=64; KT=2; lt=T-T_WVS2; }
  else { W=w_vvv; N=64; KT=2; lt=T-T_WVVV; }
  const int nt=lt/KT, kt=lt-nt*KT;
  const int col=nt*16+(l&15);
  short8v o;
  #pragma unroll
  for(int j=0;j<8;j++){
    int k=kt*32+((j>>2)<<4)+((l>>4)<<2)+(j&3);
    o[j]=f2s(W[(size_t)k*N+col]);
  }
  *(short8v*)(P+((size_t)T<<9)+(l<<3))=o;
}

// ---------------------------------------------------------------------------
// K1 (MFMA): Q,K (bf16) and NREC[0..256) = {S1(128), S2(64), sv(64)}
// 16 nodes/block, 4 waves.
// ---------------------------------------------------------------------------
__global__ __launch_bounds__(256) void k1_mfma(
  const float* __restrict__ nf, const short* __restrict__ P,
  const float* __restrict__ bq, const float* __restrict__ bk,
  const float* __restrict__ bvs,
  bf16* __restrict__ Q, bf16* __restrict__ K, bf16* __restrict__ NREC)
{
  __shared__ __align__(16) short nsF[4*512];
  __shared__ __align__(16) short vsF[4*512];
  const int t=threadIdx.x, l=t&63, w=t>>6;
  const int n0=blockIdx.x*16;
  for(int i=t;i<512;i+=256){
    int r=i>>5, c=(i&31)<<2;
    const float4 v=*(const float4*)&nf[(size_t)(n0+r)*320+c];
    short4 s; s.x=f2s(v.x); s.y=f2s(v.y); s.z=f2s(v.z); s.w=f2s(v.w);
    *(short4*)((char*)nsF+fragOff(r,c))=s;
  }
  __syncthreads();
  short8v a[4];
  #pragma unroll
  for(int kt=0;kt<4;kt++) a[kt]=*(const short8v*)((const char*)nsF+(kt<<10)+(l<<4));
  // Q and K (16 nt each; wave w: nt=w,w+4,w+8,w+12)
  #pragma unroll
  for(int ii=0;ii<4;ii++){
    int nt=w+(ii<<2);
    f32x4 accq={0.f,0.f,0.f,0.f}, acck={0.f,0.f,0.f,0.f};
    #pragma unroll
    for(int kt=0;kt<4;kt++){
      short8v bq8=*(const short8v*)(P+(((size_t)(T_WQ+nt*4+kt))<<9)+(l<<3));
      short8v bk8=*(const short8v*)(P+(((size_t)(T_WK+nt*4+kt))<<9)+(l<<3));
      accq=__builtin_amdgcn_mfma_f32_16x16x32_bf16(a[kt],bq8,accq,0,0,0);
      acck=__builtin_amdgcn_mfma_f32_16x16x32_bf16(a[kt],bk8,acck,0,0,0);
    }
    int col=(nt<<4)+(l&15);
    float bqs=bq[col], bks=bk[col];
    #pragma unroll
    for(int r=0;r<4;r++){
      int row=((l>>4)<<2)+r;
      Q[(size_t)(n0+row)*256+col]=f2b(accq[r]+bqs);
      K[(size_t)(n0+row)*256+col]=f2b(acck[r]+bks);
    }
  }
  // Vs = ns@Wv_s + bvs -> vsF A-frags (8 nt; wave w: nt=w,w+4)
  #pragma unroll
  for(int ii=0;ii<2;ii++){
    int nt=w+(ii<<2);
    f32x4 acc={0.f,0.f,0.f,0.f};
    #pragma unroll
    for(int kt=0;kt<4;kt++){
      short8v b=*(const short8v*)(P+(((size_t)(T_WVS+nt*4+kt))<<9)+(l<<3));
      acc=__builtin_amdgcn_mfma_f32_16x16x32_bf16(a[kt],b,acc,0,0,0);
    }
    int col=(nt<<4)+(l&15);
    float bv=bvs[col];
    #pragma unroll
    for(int r=0;r<4;r++){
      int row=((l>>4)<<2)+r;
      *(short*)((char*)vsF+fragOff(row,col))=f2s(acc[r]+bv);
    }
  }
  __syncthreads();
  // stage2: S1(w_ss, nt 0..7), S2(w_ssg, nt 8..11), sv(w_sv, nt 12..15)
  #pragma unroll
  for(int kt=0;kt<4;kt++) a[kt]=*(const short8v*)((const char*)vsF+(kt<<10)+(l<<4));
  #pragma unroll
  for(int ii=0;ii<4;ii++){
    int nt=w+(ii<<2);
    int bt;
    if(nt<8) bt=T_WSS+nt*4;
    else if(nt<12) bt=T_WSSG+(nt-8)*4;
    else bt=T_WSV+(nt-12)*4;
    f32x4 acc={0.f,0.f,0.f,0.f};
    #pragma unroll
    for(int kt=0;kt<4;kt++){
      short8v b=*(const short8v*)(P+(((size_t)(bt+kt))<<9)+(l<<3));
      acc=__builtin_amdgcn_mfma_f32_16x16x32_bf16(a[kt],b,acc,0,0,0);
    }
    int col=(nt<<4)+(l&15);
    #pragma unroll
    for(int r=0;r<4;r++){
      int row=((l>>4)<<2)+r;
      NREC[(size_t)(n0+row)*1216+col]=f2b(acc[r]);
    }
  }
}

// ---------------------------------------------------------------------------
// K2 (MFMA): NREC[256..1216) = {D1(3x128), D2(3x64), Wvs(3x64), Cn(3x64)}
// 16 nodes/block, 4 waves.
// ---------------------------------------------------------------------------
__global__ __launch_bounds__(256) void k2_mfma(
  const float* __restrict__ nf, const short* __restrict__ P,
  bf16* __restrict__ NREC)
{
  __shared__ __align__(16) short nvF[6*512];
  __shared__ __align__(16) short vvF[6*512];
  const int t=threadIdx.x, l=t&63, w=t>>6;
  const int n0=blockIdx.x*16;
  for(int i=t;i<3072;i+=256){
    int r=i/192, c=i-r*192;
    int v=c/3, k=c-3*v;
    float x=nf[(size_t)(n0+r)*320+128+c];
    *(short*)((char*)nvF+(k<<11)+fragOff(r,v))=f2s(x);
  }
  __syncthreads();
  // Vvn[p] = nV[p] @ Wv_v : 12 jobs (p,nt), 3 per wave
  #pragma unroll
  for(int jj=0;jj<3;jj++){
    int job=w+(jj<<2);
    int p=job>>2, nt=job&3;
    f32x4 acc={0.f,0.f,0.f,0.f};
    #pragma unroll
    for(int kt=0;kt<2;kt++){
      short8v a2=*(const short8v*)((const char*)nvF+(p<<11)+(kt<<10)+(l<<4));
      short8v b=*(const short8v*)(P+(((size_t)(T_WVV+nt*2+kt))<<9)+(l<<3));
      acc=__builtin_amdgcn_mfma_f32_16x16x32_bf16(a2,b,acc,0,0,0);
    }
    int col=(nt<<4)+(l&15);
    #pragma unroll
    for(int r=0;r<4;r++){
      int row=((l>>4)<<2)+r;
      *(short*)((char*)vvF+(p<<11)+fragOff(row,col))=f2s(acc[r]);
    }
  }
  __syncthreads();
  // stage2: 60 jobs = 3 planes x {D1:8, D2:4, Wvs:4, Cn:4}; 15 per wave
  #pragma unroll
  for(int jj=0;jj<15;jj++){
    int job=w+(jj<<2);
    int p=job/20, r20=job-p*20;
    int nt, bt, off;
    if(r20<8){ nt=r20; bt=T_WVVS+nt*2; off=256+(p<<7); }
    else if(r20<12){ nt=r20-8; bt=T_WVVG+nt*2; off=640+(p<<6); }
    else if(r20<16){ nt=r20-12; bt=T_WVS2+nt*2; off=832+(p<<6); }
    else { nt=r20-16; bt=T_WVVV+nt*2; off=1024+(p<<6); }
    f32x4 acc={0.f,0.f,0.f,0.f};
    #pragma unroll
    for(int kt=0;kt<2;kt++){
      short8v a2=*(const short8v*)((const char*)vvF+(p<<11)+(kt<<10)+(l<<4));
      short8v b=*(const short8v*)(P+(((size_t)(bt+kt))<<9)+(l<<3));
      acc=__builtin_amdgcn_mfma_f32_16x16x32_bf16(a2,b,acc,0,0,0);
    }
    int col=(nt<<4)+(l&15);
    #pragma unroll
    for(int r=0;r<4;r++){
      int row=((l>>4)<<2)+r;
      NREC[(size_t)(n0+row)*1216+off+col]=f2b(acc[r]);
    }
  }
}

// ---------------------------------------------------------------------------
// Sort-by-dst (counting sort): histogram -> scan -> scatter
// ---------------------------------------------------------------------------
__global__ __launch_bounds__(256) void k_hist(const int* __restrict__ eidx, int* __restrict__ counts){
  int e=blockIdx.x*256+threadIdx.x;
  if(e<NEDGE) atomicAdd(&counts[eidx[NEDGE+e]],1);
}

__global__ __launch_bounds__(1024) void k_scan(const int* __restrict__ counts, int* __restrict__ off, int* __restrict__ cursor){
  __shared__ int wsum[16];
  __shared__ int woff[17];
  __shared__ int carry_s;
  const int t=threadIdx.x, ln=t&63, wid=t>>6;
  if(t==0) carry_s=0;
  __syncthreads();
  for(int base=0;base<NNODE;base+=1024){
    int idx=base+t;
    int v=(idx<NNODE)?counts[idx]:0;
    int incl=v;
    #pragma unroll
    for(int o=1;o<64;o<<=1){ int x=__shfl_up(incl,o,64); if(ln>=o) incl+=x; }
    if(ln==63) wsum[wid]=incl;
    __syncthreads();
    if(t<16){
      int s=wsum[t];
      #pragma unroll
      for(int o=1;o<16;o<<=1){ int x=__shfl_up(s,o,64); if(t>=o) s+=x; }
      woff[t+1]=s;
      if(t==0) woff[0]=0;
    }
    __syncthreads();
    int excl=carry_s+woff[wid]+(incl-v);
    if(idx<NNODE){ off[idx]=excl; cursor[idx]=excl; }
    __syncthreads();
    if(t==0) carry_s+=woff[16];
    __syncthreads();
  }
  if(t==0) off[NNODE]=NEDGE;
}

__global__ __launch_bounds__(256) void k_scatter(const int* __restrict__ eidx, int* __restrict__ cursor, int* __restrict__ eord){
  int e=blockIdx.x*256+threadIdx.x;
  if(e<NEDGE){
    int d=eidx[NEDGE+e];
    int pos=atomicAdd(&cursor[d],1);
    eord[pos]=e;
  }
}

// ---------------------------------------------------------------------------
// K3 (MFMA): ef = edge_attr@We + be via matrix cores; scores -> SC.
// ---------------------------------------------------------------------------
__global__ __launch_bounds__(256) void k3_mfma(
  const float* __restrict__ eattr, const int* __restrict__ eidx,
  const short* __restrict__ P, const float* __restrict__ be,
  const bf16* __restrict__ Q, const bf16* __restrict__ K,
  float* __restrict__ SC)
{
  __shared__ __align__(16) short aeF[2*512];
  __shared__ __align__(16) float ef[16][260];
  __shared__ int ssrc[16], sdst[16];
  const int t=threadIdx.x, l=t&63, w=t>>6;
  const int e0=blockIdx.x*16;
  if(t<16){ ssrc[t]=eidx[e0+t]; sdst[t]=eidx[NEDGE+e0+t]; }
  {
    int r=t>>4, c4=(t&15)<<2;
    const float4 v=*(const float4*)&eattr[(size_t)(e0+r)*64+c4];
    short4 s; s.x=f2s(v.x); s.y=f2s(v.y); s.z=f2s(v.z); s.w=f2s(v.w);
    *(short4*)((char*)aeF+fragOff(r,c4))=s;
  }
  __syncthreads();
  {
    short8v a0=*(const short8v*)((const char*)aeF+(l<<4));
    short8v a1=*(const short8v*)((const char*)aeF+1024+(l<<4));
    #pragma unroll
    for(int ii=0;ii<4;ii++){
      int nt=w+(ii<<2);
      f32x4 acc={0.f,0.f,0.f,0.f};
      short8v b0=*(const short8v*)(P+(((size_t)(T_WE+nt*2+0))<<9)+(l<<3));
      short8v b1=*(const short8v*)(P+(((size_t)(T_WE+nt*2+1))<<9)+(l<<3));
      acc=__builtin_amdgcn_mfma_f32_16x16x32_bf16(a0,b0,acc,0,0,0);
      acc=__builtin_amdgcn_mfma_f32_16x16x32_bf16(a1,b1,acc,0,0,0);
      int col=(nt<<4)+(l&15);
      float bv=be[col];
      #pragma unroll
      for(int r=0;r<4;r++){ int row=((l>>4)<<2)+r; ef[row][col]=acc[r]+bv; }
    }
  }
  __syncthreads();
  {
    const int h=l&15, qt=l>>4;
    const int ch=h*16+(qt<<2);
    #pragma unroll
    for(int j=0;j<4;j++){
      int el=w*4+j;
      int s=ssrc[el], d=sdst[el];
      short4 qs=*(const short4*)((const short*)Q+(size_t)d*256+ch);
      short4 ks=*(const short4*)((const short*)K+(size_t)s*256+ch);
      const float4 e4=*(const float4*)&ef[el][ch];
      float p = s2f(qs.x)*(s2f(ks.x)+e4.x)
              + s2f(qs.y)*(s2f(ks.y)+e4.y)
              + s2f(qs.z)*(s2f(ks.z)+e4.z)
              + s2f(qs.w)*(s2f(ks.w)+e4.w);
      p += __shfl_xor(p,16,64);
      p += __shfl_xor(p,32,64);
      if(qt==0) SC[(size_t)(e0+el)*16+h]=p*0.25f;
    }
  }
}

// ---------------------------------------------------------------------------
// K6: per-dst-node aggregation. One wave per node, 4 nodes/block. No atomics.
// ---------------------------------------------------------------------------
__global__ __launch_bounds__(256) void k6_agg(
  const int* __restrict__ eidx, const float* __restrict__ esh,
  const bf16* __restrict__ NREC, const float* __restrict__ SC,
  const int* __restrict__ OFF, const int* __restrict__ EORD,
  const float* __restrict__ b_ms, const float* __restrict__ b_mg,
  float* __restrict__ AGS, float* __restrict__ AGV)
{
  const int l = threadIdx.x & 63;
  const int n = blockIdx.x*4 + (threadIdx.x>>6);
  const int beg=OFF[n], end=OFF[n+1];
  const float bmsa=b_ms[l], bmsb=b_ms[64+l], bmgv=b_mg[l];

  float mh=-1e30f;
  for(int i=beg;i<end;i++){
    int e=EORD[i];
    if(l<16) mh=fmaxf(mh, SC[(size_t)e*16+l]);
  }
  float dh=0.f;
  for(int i=beg;i<end;i++){
    int e=EORD[i];
    if(l<16) dh+=__expf(SC[(size_t)e*16+l]-mh);
  }
  float rdh = (end>beg && l<16) ? 1.f/dh : 0.f;

  float as0=0.f,as1=0.f,av0acc=0.f,av1acc=0.f,av2acc=0.f;
  for(int i=beg;i<end;i++){
    const int e=EORD[i];
    const int s=eidx[e];
    const float4 sh4=*(const float4*)&esh[(size_t)e*4];
    const float shs=sh4.x, sh0=sh4.y, sh1=sh4.z, sh2=sh4.w;
    float av=(l<16)? __expf(SC[(size_t)e*16+l]-mh)*rdh : 0.f;
    const float att=wred64(av)*(1.f/16.f);

    const bf16* R = NREC + (size_t)s*1216;
    const float s1a=b2f(R[l]),      s1b=b2f(R[64+l]);
    const float s2 =b2f(R[128+l]),  svv=b2f(R[192+l]);
    const float d1a0=b2f(R[256+l]),     d1a1=b2f(R[256+128+l]),  d1a2=b2f(R[256+256+l]);
    const float d1b0=b2f(R[256+64+l]),  d1b1=b2f(R[256+192+l]),  d1b2=b2f(R[256+320+l]);
    const float d20=b2f(R[640+l]),  d21=b2f(R[640+64+l]),  d22=b2f(R[640+128+l]);
    const float w0 =b2f(R[832+l]),  w1 =b2f(R[832+64+l]),  w2 =b2f(R[832+128+l]);
    const float c0 =b2f(R[1024+l]), c1 =b2f(R[1024+64+l]), c2 =b2f(R[1024+128+l]);

    float msa = shs*s1a + d1a0*sh0+d1a1*sh1+d1a2*sh2 + bmsa;
    float msb = shs*s1b + d1b0*sh0+d1b1*sh1+d1b2*sh2 + bmsb;
    float mgv = shs*s2  + d20*sh0 +d21*sh1 +d22*sh2  + bmgv;

    float sum = wred64(msa+msb+mgv);
    float sq  = wred64(msa*msa+msb*msb+mgv*mgv);
    float mean = sum*(1.f/192.f);
    float var  = sq*(1.f/192.f) - mean*mean;
    float rs   = rsqrtf(var + 1e-5f);

    float cr0 = c1*sh2 - c2*sh1;
    float cr1 = c2*sh0 - c0*sh2;
    float cr2 = c0*sh1 - c1*sh0;
    float mv0 = svv*sh0 + shs*w0 + cr0;
    float mv1 = svv*sh1 + shs*w1 + cr1;
    float mv2 = svv*sh2 + shs*w2 + cr2;
    float vsq = wred64(mv0*mv0+mv1*mv1+mv2*mv2);
    float vn  = rsqrtf(vsq*(1.f/64.f) + 1e-5f);

    float sga=(msa-mean)*rs, sgb=(msb-mean)*rs, sgg=(mgv-mean)*rs;
    float wV = vn * sigm(sgg) * att;
    as0 += sga*sigm(sga)*att;
    as1 += sgb*sigm(sgb)*att;
    av0acc += mv0*wV;
    av1acc += mv1*wV;
    av2acc += mv2*wV;
  }
  AGS[(size_t)n*128+l]     =as0;
  AGS[(size_t)n*128+64+l]  =as1;
  AGV[(size_t)n*192+l]     =av0acc;
  AGV[(size_t)n*192+64+l]  =av1acc;
  AGV[(size_t)n*192+128+l] =av2acc;
}

// ---------------------------------------------------------------------------
// K7 (MFMA): final node update. 16 nodes/block, 4 waves.
// ---------------------------------------------------------------------------
__global__ __launch_bounds__(256) void k7_mfma(
  const float* __restrict__ nf,
  const float* __restrict__ AGS, const float* __restrict__ AGV,
  const short* __restrict__ P,
  const float* __restrict__ bo_s, const float* __restrict__ b1_s, const float* __restrict__ b2_s,
  float* __restrict__ out)
{
  __shared__ float xs[16][132];
  __shared__ float xv[16][196];
  __shared__ float ff[16][196];
  __shared__ __align__(16) short asA[4*512];
  __shared__ __align__(16) short avA[6*512];
  __shared__ float smean[16], srs[16], svn[16];
  const int t=threadIdx.x, l=t&63, w=t>>6;
  const int n0=blockIdx.x*16;

  for(int i=t;i<2048;i+=256){ int r=i>>7,c=i&127; xs[r][c]=nf[(size_t)(n0+r)*320+c]; }
  for(int i=t;i<3072;i+=256){ int r=i/192,cc=i-r*192; int k=cc>>6,u=cc&63; xv[r][cc]=nf[(size_t)(n0+r)*320+128+u*3+k]; }
  for(int i=t;i<512;i+=256){
    int r=i>>5, c=(i&31)<<2;
    const float4 v=*(const float4*)&AGS[(size_t)(n0+r)*128+c];
    short4 s; s.x=f2s(v.x); s.y=f2s(v.y); s.z=f2s(v.z); s.w=f2s(v.w);
    *(short4*)((char*)asA+fragOff(r,c))=s;
  }
  for(int i=t;i<768;i+=256){
    int r=i/48, c=(i-r*48)<<2;
    const float4 v=*(const float4*)&AGV[(size_t)(n0+r)*192+c];
    int p=c>>6,u=c&63;
    short4 s; s.x=f2s(v.x); s.y=f2s(v.y); s.z=f2s(v.z); s.w=f2s(v.w);
    *(short4*)((char*)avA+(p<<11)+fragOff(r,u))=s;
  }
  __syncthreads();

  {
    short8v a[4];
    #pragma unroll
    for(int kt=0;kt<4;kt++) a[kt]=*(const short8v*)((const char*)asA+(kt<<10)+(l<<4));
    #pragma unroll
    for(int ii=0;ii<2;ii++){
      int nt=w+(ii<<2);
      f32x4 acc={0.f,0.f,0.f,0.f};
      #pragma unroll
      for(int kt=0;kt<4;kt++){
        short8v b=*(const short8v*)(P+(((size_t)(T_WOS+nt*4+kt))<<9)+(l<<3));
        acc=__builtin_amdgcn_mfma_f32_16x16x32_bf16(a[kt],b,acc,0,0,0);
      }
      int col=(nt<<4)+(l&15);
      float bv=bo_s[col];
      #pragma unroll
      for(int r=0;r<4;r++){ int row=((l>>4)<<2)+r; xs[row][col]+=acc[r]+bv; }
    }
    #pragma unroll
    for(int ii=0;ii<3;ii++){
      int tid=w*3+ii, p=tid>>2, nt2=tid&3;
      f32x4 acc={0.f,0.f,0.f,0.f};
      #pragma unroll
      for(int kt=0;kt<2;kt++){
        short8v a2=*(const short8v*)((const char*)avA+(((p<<1)+kt)<<10)+(l<<4));
        short8v b=*(const short8v*)(P+(((size_t)(T_WOV+nt2*2+kt))<<9)+(l<<3));
        acc=__builtin_amdgcn_mfma_f32_16x16x32_bf16(a2,b,acc,0,0,0);
      }
      int col=(p<<6)+(nt2<<4)+(l&15);
      #pragma unroll
      for(int r=0;r<4;r++){ int row=((l>>4)<<2)+r; xv[row][col]+=acc[r]; }
    }
  }
  __syncthreads();

  {
    const int nn=t>>4, g=t&15;
    float sum=0,sq=0;
    #pragma unroll
    for(int j=0;j<8;j++){ float x=xs[nn][g+16*j]; sum+=x; sq+=x*x; }
    sum=gred16(sum); sq=gred16(sq);
    float mean=sum*(1.f/128.f);
    float var=sq*(1.f/128.f)-mean*mean;
    float vsq=0;
    #pragma unroll
    for(int j=0;j<12;j++){ float x=xv[nn][g+16*j]; vsq+=x*x; }
    vsq=gred16(vsq);
    if(g==0){ smean[nn]=mean; srs[nn]=rsqrtf(var+1e-5f); svn[nn]=rsqrtf(vsq*(1.f/64.f)+1e-5f); }
  }
  __syncthreads();

  for(int i=t;i<512;i+=256){
    int r=i>>5, c=(i&31)<<2;
    float m=smean[r], rs=srs[r];
    float4 v=*(float4*)&xs[r][c];
    v.x=(v.x-m)*rs; v.y=(v.y-m)*rs; v.z=(v.z-m)*rs; v.w=(v.w-m)*rs;
    *(float4*)&xs[r][c]=v;
    short4 s; s.x=f2s(v.x); s.y=f2s(v.y); s.z=f2s(v.z); s.w=f2s(v.w);
    *(short4*)((char*)asA+fragOff(r,c))=s;
  }
  for(int i=t;i<768;i+=256){
    int r=i/48, c=(i-r*48)<<2;
    float vn=svn[r];
    float4 v=*(float4*)&xv[r][c];
    v.x*=vn; v.y*=vn; v.z*=vn; v.w*=vn;
    *(float4*)&xv[r][c]=v;
    int p=c>>6,u=c&63;
    short4 s; s.x=f2s(v.x); s.y=f2s(v.y); s.z=f2s(v.z); s.w=f2s(v.w);
    *(short4*)((char*)avA+(p<<11)+fragOff(r,u))=s;
  }
  __syncthreads();

  {
    short8v a[4];
    #pragma unroll
    for(int kt=0;kt<4;kt++) a[kt]=*(const short8v*)((const char*)asA+(kt<<10)+(l<<4));
    #pragma unroll
    for(int ii=0;ii<3;ii++){
      int nt=w+(ii<<2);
      f32x4 acc={0.f,0.f,0.f,0.f};
      #pragma unroll
      for(int kt=0;kt<4;kt++){
        short8v b=*(const short8v*)(P+(((size_t)(T_W1S+nt*4+kt))<<9)+(l<<3));
        acc=__builtin_amdgcn_mfma_f32_16x16x32_bf16(a[kt],b,acc,0,0,0);
      }
      int col=(nt<<4)+(l&15);
      float bv=b1_s[col];
      #pragma unroll
      for(int r=0;r<4;r++){ int row=((l>>4)<<2)+r; ff[row][col]=acc[r]+bv; }
    }
  }
  __syncthreads();

  f32x4 g4acc[3];
  {
    #pragma unroll
    for(int ii=0;ii<3;ii++){
      int tid=w*3+ii, p=tid>>2, nt2=tid&3;
      f32x4 acc={0.f,0.f,0.f,0.f};
      #pragma unroll
      for(int kt=0;kt<2;kt++){
        short8v a2=*(const short8v*)((const char*)avA+(((p<<1)+kt)<<10)+(l<<4));
        short8v b=*(const short8v*)(P+(((size_t)(T_W1V+nt2*2+kt))<<9)+(l<<3));
        acc=__builtin_amdgcn_mfma_f32_16x16x32_bf16(a2,b,acc,0,0,0);
      }
      g4acc[ii]=acc;
    }
    for(int i=t;i<512;i+=256){
      int r=i>>5, c=(i&31)<<2;
      float4 v=*(float4*)&ff[r][c];
      v.x=v.x*sigm(v.x); v.y=v.y*sigm(v.y); v.z=v.z*sigm(v.z); v.w=v.w*sigm(v.w);
      short4 s; s.x=f2s(v.x); s.y=f2s(v.y); s.z=f2s(v.z); s.w=f2s(v.w);
      *(short4*)((char*)asA+fragOff(r,c))=s;
    }
  }
  __syncthreads();

  {
    #pragma unroll
    for(int ii=0;ii<3;ii++){
      int tid=w*3+ii, p=tid>>2, nt2=tid&3;
      int uu=(nt2<<4)+(l&15);
      #pragma unroll
      for(int r=0;r<4;r++){
        int row=((l>>4)<<2)+r;
        float val=g4acc[ii][r]*sigm(ff[row][128+uu]);
        *(short*)((char*)avA+(p<<11)+fragOff(row,uu))=f2s(val);
      }
    }
  }
  __syncthreads();

  {
    short8v a[4];
    #pragma unroll
    for(int kt=0;kt<4;kt++) a[kt]=*(const short8v*)((const char*)asA+(kt<<10)+(l<<4));
    #pragma unroll
    for(int ii=0;ii<2;ii++){
      int nt=w+(ii<<2);
      f32x4 acc={0.f,0.f,0.f,0.f};
      #pragma unroll
      for(int kt=0;kt<4;kt++){
        short8v b=*(const short8v*)(P+(((size_t)(T_W2S+nt*4+kt))<<9)+(l<<3));
        acc=__builtin_amdgcn_mfma_f32_16x16x32_bf16(a[kt],b,acc,0,0,0);
      }
      int col=(nt<<4)+(l&15);
      float bv=b2_s[col];
      #pragma unroll
      for(int r=0;r<4;r++){ int row=((l>>4)<<2)+r; xs[row][col]+=acc[r]+bv; }
    }
    #pragma unroll
    for(int ii=0;ii<3;ii++){
      int tid=w*3+ii, p=tid>>2, nt2=tid&3;
      f32x4 acc={0.f,0.f,0.f,0.f};
      #pragma unroll
      for(int kt=0;kt<2;kt++){
        short8v a2=*(const short8v*)((const char*)avA+(((p<<1)+kt)<<10)+(l<<4));
        short8v b=*(const short8v*)(P+(((size_t)(T_W2V+nt2*2+kt))<<9)+(l<<3));
        acc=__builtin_amdgcn_mfma_f32_16x16x32_bf16(a2,b,acc,0,0,0);
      }
      int col=(p<<6)+(nt2<<4)+(l&15);
      #pragma unroll
      for(int r=0;r<4;r++){ int row=((l>>4)<<2)+r; xv[row][col]+=acc[r]; }
    }
  }
  __syncthreads();

  {
    const int nn=t>>4, g=t&15;
    float sum=0,sq=0;
    #pragma unroll
    for(int j=0;j<8;j++){ float x=xs[nn][g+16*j]; sum+=x; sq+=x*x; }
    sum=gred16(sum); sq=gred16(sq);
    float mean=sum*(1.f/128.f);
    float var=sq*(1.f/128.f)-mean*mean;
    float vsq=0;
    #pragma unroll
    for(int j=0;j<12;j++){ float x=xv[nn][g+16*j]; vsq+=x*x; }
    vsq=gred16(vsq);
    if(g==0){ smean[nn]=mean; srs[nn]=rsqrtf(var+1e-5f); svn[nn]=rsqrtf(vsq*(1.f/64.f)+1e-5f); }
  }
  __syncthreads();

  for(int i=t;i<16*320;i+=256){
    int nn=i/320, c=i-nn*320;
    float v;
    if(c<128) v=(xs[nn][c]-smean[nn])*srs[nn];
    else { int j=c-128; int u=j/3, k=j-u*3; v=xv[nn][(k<<6)+u]*svn[nn]; }
    out[(size_t)(n0+nn)*320+c]=v;
  }
}

// ---------------------------------------------------------------------------
extern "C" void kernel_launch(void* const* d_in, const int* in_sizes, int n_in,
                              void* d_out, int out_size, void* d_ws, size_t ws_size,
                              hipStream_t stream)
{
  (void)in_sizes; (void)n_in; (void)out_size; (void)ws_size;
  const float* nf    =(const float*)d_in[0];
  const float* eattr =(const float*)d_in[1];
  const float* esh   =(const float*)d_in[2];
  const float* Wq    =(const float*)d_in[3];  const float* bq  =(const float*)d_in[4];
  const float* Wk    =(const float*)d_in[5];  const float* bk  =(const float*)d_in[6];
  const float* We    =(const float*)d_in[7];  const float* be  =(const float*)d_in[8];
  const float* Wv_s  =(const float*)d_in[9];  const float* bv_s=(const float*)d_in[10];
  const float* Wv_v  =(const float*)d_in[11];
  const float* w_ss  =(const float*)d_in[12]; const float* w_vv_s=(const float*)d_in[13];
  const float* w_ssg =(const float*)d_in[14]; const float* w_vvg =(const float*)d_in[15];
  const float* b_ms  =(const float*)d_in[16]; const float* b_mg  =(const float*)d_in[17];
  const float* w_sv  =(const float*)d_in[18]; const float* w_vs  =(const float*)d_in[19];
  const float* w_vvv =(const float*)d_in[20];
  const float* Wo_s  =(const float*)d_in[21]; const float* bo_s  =(const float*)d_in[22];
  const float* Wo_v  =(const float*)d_in[23];
  const float* W1_s  =(const float*)d_in[24]; const float* b1_s  =(const float*)d_in[25];
  const float* W1_v  =(const float*)d_in[26];
  const float* W2_s  =(const float*)d_in[27]; const float* b2_s  =(const float*)d_in[28];
  const float* W2_v  =(const float*)d_in[29];
  const int*   eidx  =(const int*)d_in[30];
  float* out=(float*)d_out;

  char* w=(char*)d_ws;
  bf16* Q    =(bf16*)w;  w+=(size_t)NNODE*256*2;
  bf16* Kb   =(bf16*)w;  w+=(size_t)NNODE*256*2;
  bf16* NREC =(bf16*)w;  w+=(size_t)NNODE*1216*2;
  float* SC  =(float*)w; w+=(size_t)NEDGE*16*4;
  float* AGS =(float*)w; w+=(size_t)NNODE*128*4;
  float* AGV =(float*)w; w+=(size_t)NNODE*192*4;
  short* P   =(short*)w; w+=(size_t)T_TOT*512*2;
  int* COUNTS=(int*)w;   w+=(size_t)NNODE*4;
  int* OFFb  =(int*)w;   w+=(size_t)(NNODE+1)*4;
  int* CURSOR=(int*)w;   w+=(size_t)NNODE*4;
  int* EORDb =(int*)w;   w+=(size_t)NEDGE*4;

  hipMemsetAsync(COUNTS,0,(size_t)NNODE*4,stream);

  k_prep    <<<T_TOT,64,0,stream>>>(Wo_s,Wo_v,W1_s,W1_v,W2_s,W2_v,We,
                                    Wq,Wk,Wv_s,w_ss,w_ssg,w_sv,
                                    Wv_v,w_vv_s,w_vvg,w_vs,w_vvv,P);
  k_hist    <<<(NEDGE+255)/256,256,0,stream>>>(eidx,COUNTS);
  k_scan    <<<1,1024,0,stream>>>(COUNTS,OFFb,CURSOR);
  k_scatter <<<(NEDGE+255)/256,256,0,stream>>>(eidx,CURSOR,EORDb);
  k1_mfma   <<<NNODE/16,256,0,stream>>>(nf,P,bq,bk,bv_s,Q,Kb,NREC);
  k2_mfma   <<<NNODE/16,256,0,stream>>>(nf,P,NREC);
  k3_mfma   <<<NEDGE/16,256,0,stream>>>(eattr,eidx,P,be,Q,Kb,SC);
  k6_agg    <<<NNODE/4,256,0,stream>>>(eidx,esh,NREC,SC,OFFb,EORDb,b_ms,b_mg,AGS,AGV);
  k7_mfma   <<<NNODE/16,256,0,stream>>>(nf,AGS,AGV,P,bo_s,b1_s,b2_s,out);
}